// Round 1
// 635.686 us; speedup vs baseline: 1.1114x; 1.1114x over previous
//
#include <hip/hip_runtime.h>

typedef __attribute__((ext_vector_type(8))) __bf16 bf16x8;
typedef __attribute__((ext_vector_type(4))) __bf16 bf16x4;
typedef __attribute__((ext_vector_type(4))) float floatx4;
typedef void __attribute__((address_space(3))) lds_void_t;
typedef const void __attribute__((address_space(1))) gbl_void_t;

#define D_MODEL 1024
#define SEQ     2048
#define BATCH   2
#define NH      16
#define DK      64
#define DFF     4096
#define NTOK    (BATCH * SEQ)   // 4096
#define QKVS    3072            // fused qkv row stride

__device__ __forceinline__ float gelu_exact(float x) {
    return 0.5f * x * (1.0f + erff(x * 0.70710678118654752f));
}

// ---------------- fp32 -> bf16 weight cast, 8 elems/thread --------------------------
__global__ __launch_bounds__(256) void cast_f32_bf16(const float* __restrict__ src,
                                                     __bf16* __restrict__ dst, int n) {
    int i = (blockIdx.x * 256 + threadIdx.x) * 8;
    if (i >= n) return;
    floatx4 a = *(const floatx4*)(src + i);
    floatx4 b = *(const floatx4*)(src + i + 4);
    bf16x8 o;
    for (int j = 0; j < 4; ++j) { o[j] = (__bf16)a[j]; o[4 + j] = (__bf16)b[j]; }
    *(bf16x8*)(dst + i) = o;
}

// ---------------- LayerNorm: one wave per row of 1024; fp32 in, bf16 out ------------
__global__ __launch_bounds__(64) void ln_kernel(const float* __restrict__ x,
                                                const float* __restrict__ g,
                                                const float* __restrict__ b,
                                                __bf16* __restrict__ out) {
    int row = blockIdx.x, lane = threadIdx.x, base = lane * 16;
    const float* xr = x + (size_t)row * D_MODEL + base;
    float v[16];
    for (int j = 0; j < 4; ++j) {
        floatx4 a = *(const floatx4*)(xr + 4 * j);
        for (int i = 0; i < 4; ++i) v[4 * j + i] = a[i];
    }
    float s = 0.f, sq = 0.f;
    for (int i = 0; i < 16; ++i) { s += v[i]; sq += v[i] * v[i]; }
    for (int o = 1; o < 64; o <<= 1) { s += __shfl_xor(s, o); sq += __shfl_xor(sq, o); }
    float mu = s * (1.0f / D_MODEL);
    float var = sq * (1.0f / D_MODEL) - mu * mu;
    float rstd = rsqrtf(fmaxf(var, 0.f) + 1e-5f);

    const floatx4* gp = (const floatx4*)(g + base);
    const floatx4* bp = (const floatx4*)(b + base);
    bf16x8 o0, o1;
    for (int j = 0; j < 2; ++j) {
        floatx4 gv0 = gp[2 * j], gv1 = gp[2 * j + 1];
        floatx4 bv0 = bp[2 * j], bv1 = bp[2 * j + 1];
        for (int i = 0; i < 4; ++i) {
            float r0 = (v[8 * j + i] - mu) * rstd * gv0[i] + bv0[i];
            float r1 = (v[8 * j + 4 + i] - mu) * rstd * gv1[i] + bv1[i];
            if (j == 0) { o0[i] = (__bf16)r0; o0[4 + i] = (__bf16)r1; }
            else        { o1[i] = (__bf16)r0; o1[4 + i] = (__bf16)r1; }
        }
    }
    bf16x8* op = (bf16x8*)(out + (size_t)row * D_MODEL + base);
    op[0] = o0; op[1] = o1;
}

// ---------------- GEMM (m97-style): C = A@W^T + bias (+gelu) (+res) -----------------
// A, W bf16 K-contiguous. 128x128 tile, BK=32, 4 waves, global_load_lds width=16.
// TRIBIAS: bias segmented per 1024 cols (fused QKV).
template <typename OutT, bool GELU, bool TRIBIAS>
__global__ __launch_bounds__(256) void gemm_bt(const __bf16* __restrict__ A,
                                               const __bf16* __restrict__ W,
                                               const float* __restrict__ bias0,
                                               const float* __restrict__ bias1,
                                               const float* __restrict__ bias2,
                                               const float* __restrict__ res,
                                               OutT* __restrict__ out,
                                               int M, int N, int K) {
    __shared__ __bf16 As[128][32];
    __shared__ __bf16 Ws[128][32];

    int m0 = blockIdx.y * 128, n0 = blockIdx.x * 128;
    int t = threadIdx.x;
    int lane = t & 63, wave = t >> 6;
    int wm = (wave >> 1) * 64, wn = (wave & 1) * 64;
    int fr = lane & 15, quad = lane >> 4;
    int srow = t >> 2, scol = (t & 3) * 8;

    floatx4 acc[4][4] = {};

    const __bf16* Ab = A + (size_t)(m0 + srow) * K + scol;
    const __bf16* Wb = W + (size_t)(n0 + srow) * K + scol;
    lds_void_t* lA0 = (lds_void_t*)&As[wave * 16][0];
    lds_void_t* lA1 = (lds_void_t*)&As[64 + wave * 16][0];
    lds_void_t* lW0 = (lds_void_t*)&Ws[wave * 16][0];
    lds_void_t* lW1 = (lds_void_t*)&Ws[64 + wave * 16][0];

    for (int k0 = 0; k0 < K; k0 += 32) {
        __syncthreads();
        __builtin_amdgcn_global_load_lds((gbl_void_t*)(Ab + k0), lA0, 16, 0, 0);
        __builtin_amdgcn_global_load_lds((gbl_void_t*)(Ab + (size_t)64 * K + k0), lA1, 16, 0, 0);
        __builtin_amdgcn_global_load_lds((gbl_void_t*)(Wb + k0), lW0, 16, 0, 0);
        __builtin_amdgcn_global_load_lds((gbl_void_t*)(Wb + (size_t)64 * K + k0), lW1, 16, 0, 0);
        __syncthreads();

        bf16x8 af[4], wf[4];
        for (int i = 0; i < 4; ++i) af[i] = *(const bf16x8*)&As[wm + i * 16 + fr][quad * 8];
        for (int i = 0; i < 4; ++i) wf[i] = *(const bf16x8*)&Ws[wn + i * 16 + fr][quad * 8];
        for (int mi = 0; mi < 4; ++mi)
            for (int ni = 0; ni < 4; ++ni)
                acc[mi][ni] = __builtin_amdgcn_mfma_f32_16x16x32_bf16(af[mi], wf[ni], acc[mi][ni], 0, 0, 0);
    }

    for (int ni = 0; ni < 4; ++ni) {
        int col = n0 + wn + ni * 16 + fr;
        const float* bp = bias0;
        int bcol = col;
        if (TRIBIAS) { bp = col < 1024 ? bias0 : (col < 2048 ? bias1 : bias2); bcol = col & 1023; }
        float bv = bp[bcol];
        for (int mi = 0; mi < 4; ++mi) {
            for (int r = 0; r < 4; ++r) {
                int row = m0 + wm + mi * 16 + quad * 4 + r;
                float v = acc[mi][ni][r] + bv;
                if (GELU) v = gelu_exact(v);
                if (res) v += res[(size_t)row * N + col];
                out[(size_t)row * N + col] = (OutT)v;
            }
        }
    }
}

// ---------------- V transpose: qkv v-part [b][s][2048+h*64+d] -> vt[b][h][d][s] -----
__global__ __launch_bounds__(256) void transpose_v(const __bf16* __restrict__ qkv,
                                                   __bf16* __restrict__ vt) {
    __shared__ __bf16 tile[64][72];
    int b = blockIdx.z, h = blockIdx.y, s0 = blockIdx.x * 64;
    int t = threadIdx.x;
    int dl = (t & 7) * 8, sl = t >> 3;
    for (int p = 0; p < 2; ++p) {
        int s = sl + p * 32;
        bf16x8 val = *(const bf16x8*)(qkv + (size_t)(b * SEQ + s0 + s) * QKVS + 2048 + h * DK + dl);
        *(bf16x8*)&tile[s][dl] = val;
    }
    __syncthreads();
    int sl2 = (t & 7) * 8, d = t >> 3;
    for (int p = 0; p < 2; ++p) {
        int dd = d + p * 32;
        bf16x8 val;
        for (int j = 0; j < 8; ++j) val[j] = tile[sl2 + j][dd];
        *(bf16x8*)(vt + ((size_t)(b * NH + h) * DK + dd) * SEQ + s0 + sl2) = val;
    }
}

// ---------------- Flash attention, transposed-score layout --------------------------
// 1 wave = 16 q-rows, 128-key tiles. Scores via mfma(K,Q): row=key, col=query(fr)
// -> each lane owns one query's 32 scores: local reg-tree reductions + only 2
// chained shfls (xor 16,32) for max and sum. P packed b64 into per-wave LDS,
// read back as PV A-fragments. alpha/l broadcast to C-layout lanes via 4 shfls.
//
// Latency restructure (this round): batch-issue ALL 16 K b128 loads into register
// arrays before the QK MFMA cluster (1 vmcnt round-trip instead of 8), and issue
// ALL 16 V b128 loads right after QK so their latency hides under the softmax
// VALU chain (T14 issue-early/consume-late). PV batches its 4 ds_read_b128 ahead
// of the MFMA cluster. Costs ~+90 VGPR (occupancy 4->3 waves/SIMD) -- the right
// trade in a latency-bound regime (MfmaUtil was 4.5%).
__global__ __launch_bounds__(256) void attn_kernel(const __bf16* __restrict__ qkv,
                                                   const __bf16* __restrict__ vt,
                                                   __bf16* __restrict__ ctx) {
    __shared__ __bf16 Plds[4][16][136];   // [wave][query][128 keys + 8 pad]
    int b = blockIdx.z, h = blockIdx.y;
    int wave = threadIdx.x >> 6, lane = threadIdx.x & 63;
    int q0 = blockIdx.x * 64 + wave * 16;
    int fr = lane & 15, quad = lane >> 4;
    const float scale = 0.125f;   // 1/sqrt(64)

    // Q B-frag: B[n=fr(query)][k=quad*8+j(d)]
    const __bf16* qp = qkv + (size_t)(b * SEQ + q0 + fr) * QKVS + h * DK + quad * 8;
    bf16x8 qf0 = *(const bf16x8*)qp;
    bf16x8 qf1 = *(const bf16x8*)(qp + 32);

    const __bf16* kbase = qkv + (size_t)b * SEQ * QKVS + 1024 + h * DK + quad * 8;
    const __bf16* vtbase = vt + (size_t)(b * NH + h) * DK * SEQ;

    floatx4 o[4] = {};                 // C layout: row=query quad*4+r, col=d ti*16+fr
    float m_i = -1e30f, l_i = 0.f;     // per query fr (replicated over quads)

    for (int k0 = 0; k0 < SEQ; k0 += 128) {
        // ---- batched K loads: issue all 16 b128 loads, then one wait ----
        bf16x8 kA[8], kB[8];
#pragma unroll
        for (int f = 0; f < 8; ++f) {
            const __bf16* kp = kbase + (size_t)(k0 + f * 16 + fr) * QKVS;
            kA[f] = *(const bf16x8*)kp;
            kB[f] = *(const bf16x8*)(kp + 32);
        }
        // ---- QK^T MFMA cluster (K regs die here) ----
        floatx4 s[8];
#pragma unroll
        for (int f = 0; f < 8; ++f) {
            floatx4 z = {0.f, 0.f, 0.f, 0.f};
            z = __builtin_amdgcn_mfma_f32_16x16x32_bf16(kA[f], qf0, z, 0, 0, 0);
            s[f] = __builtin_amdgcn_mfma_f32_16x16x32_bf16(kB[f], qf1, z, 0, 0, 0);
        }
        // ---- batched V loads for THIS tile: independent of softmax, issue now
        //      so ~L2 latency hides under the softmax VALU chain ----
        bf16x8 vf[4][4];
#pragma unroll
        for (int c = 0; c < 4; ++c)
#pragma unroll
            for (int ti = 0; ti < 4; ++ti)
                vf[c][ti] = *(const bf16x8*)(vtbase + (size_t)(ti * 16 + fr) * SEQ + k0 + c * 32 + quad * 8);

        // ---- online softmax for query fr: local tree + 2 chained shfls ----
        float mx = s[0][0];
#pragma unroll
        for (int f = 0; f < 8; ++f)
#pragma unroll
            for (int r = 0; r < 4; ++r) mx = fmaxf(mx, s[f][r]);
        mx *= scale;
        mx = fmaxf(mx, __shfl_xor(mx, 16));
        mx = fmaxf(mx, __shfl_xor(mx, 32));
        float mn = fmaxf(m_i, mx);
        float alpha = __expf(m_i - mn);
        m_i = mn;
        float rs = 0.f;
#pragma unroll
        for (int f = 0; f < 8; ++f) {
            bf16x4 pk;
#pragma unroll
            for (int r = 0; r < 4; ++r) {
                float p = __expf(s[f][r] * scale - mn);
                rs += p;
                pk[r] = (__bf16)p;
            }
            *(bf16x4*)&Plds[wave][fr][f * 16 + quad * 4] = pk;   // ds_write_b64
        }
        rs += __shfl_xor(rs, 16);
        rs += __shfl_xor(rs, 32);
        l_i = l_i * alpha + rs;
        // broadcast alpha to o-layout lanes (query quad*4+r held by lane quad*4+r)
        float aB[4];
#pragma unroll
        for (int r = 0; r < 4; ++r) aB[r] = __shfl(alpha, quad * 4 + r);
#pragma unroll
        for (int ti = 0; ti < 4; ++ti)
#pragma unroll
            for (int r = 0; r < 4; ++r) o[ti][r] *= aB[r];
        __threadfence_block();   // order wave-private LDS writes -> cross-lane reads
        // ---- PV: batch the 4 P ds_read_b128, then pure MFMA cluster ----
        bf16x8 pa[4];
#pragma unroll
        for (int c = 0; c < 4; ++c)
            pa[c] = *(const bf16x8*)&Plds[wave][fr][c * 32 + quad * 8];
#pragma unroll
        for (int c = 0; c < 4; ++c)
#pragma unroll
            for (int ti = 0; ti < 4; ++ti)
                o[ti] = __builtin_amdgcn_mfma_f32_16x16x32_bf16(pa[c], vf[c][ti], o[ti], 0, 0, 0);
        __threadfence_block();   // reads done before next iteration's writes
    }
    float lB[4];
#pragma unroll
    for (int r = 0; r < 4; ++r) lB[r] = __shfl(l_i, quad * 4 + r);
#pragma unroll
    for (int ti = 0; ti < 4; ++ti)
#pragma unroll
        for (int r = 0; r < 4; ++r)
            ctx[(size_t)(b * SEQ + q0 + quad * 4 + r) * D_MODEL + h * DK + ti * 16 + fr] =
                (__bf16)(o[ti][r] / lB[r]);
}

// -----------------------------------------------------------------------------------
// Inputs fp32, output fp32. Workspace exactly 72 MiB:
//   [0,6M):   wqkvB (wq,wk,wv adjacent -> one [3072][1024] matrix)
//   [6,8M):   woB      [8,16M): w1B      [16,24M): w2B
//   [24,40M): h1 (dead after qkv-gemm) -> x1 fp32 trunk
//   [40,64M): qkv [4096][3072]  -> (dead after attn) ffh lower part
//   [64,72M): vt                -> (dead after attn) ffh upper part; ffh = [40,72M)
//   d_out:    ctx -> h2 -> final out
extern "C" void kernel_launch(void* const* d_in, const int* in_sizes, int n_in,
                              void* d_out, int out_size, void* d_ws, size_t ws_size,
                              hipStream_t stream) {
    const float* x   = (const float*)d_in[0];
    const float* wq  = (const float*)d_in[1];
    const float* bq  = (const float*)d_in[2];
    const float* wk  = (const float*)d_in[3];
    const float* bk  = (const float*)d_in[4];
    const float* wv  = (const float*)d_in[5];
    const float* bv  = (const float*)d_in[6];
    const float* wo  = (const float*)d_in[7];
    const float* bo  = (const float*)d_in[8];
    const float* w1  = (const float*)d_in[9];
    const float* b1  = (const float*)d_in[10];
    const float* w2  = (const float*)d_in[11];
    const float* b2  = (const float*)d_in[12];
    const float* g1  = (const float*)d_in[13];
    const float* be1 = (const float*)d_in[14];
    const float* g2  = (const float*)d_in[15];
    const float* be2 = (const float*)d_in[16];
    float* out = (float*)d_out;

    char* ws = (char*)d_ws;
    const size_t MB = 1024 * 1024;
    __bf16* wqkvB = (__bf16*)(ws);                 // [0,6M)
    __bf16* woB   = (__bf16*)(ws + 6 * MB);
    __bf16* w1B   = (__bf16*)(ws + 8 * MB);
    __bf16* w2B   = (__bf16*)(ws + 16 * MB);
    __bf16* h1    = (__bf16*)(ws + 24 * MB);       // dead after qkv-gemm
    float*  x1    = (float*)(ws + 24 * MB);        // fp32 trunk [24,40M)
    __bf16* qkv   = (__bf16*)(ws + 40 * MB);       // [40,64M)
    __bf16* vt    = (__bf16*)(ws + 64 * MB);       // [64,72M)
    __bf16* ffh   = (__bf16*)(ws + 40 * MB);       // [40,72M) after qkv+vt die
    __bf16* ctx   = (__bf16*)d_out;                // d_out scratch [0,8M)
    __bf16* h2    = (__bf16*)d_out;                // d_out scratch (after ctx dies)

    const int NDD = D_MODEL * D_MODEL;   // 1M
    const int NDF = D_MODEL * DFF;       // 4M
    cast_f32_bf16<<<NDD / 2048, 256, 0, stream>>>(wq, wqkvB, NDD);
    cast_f32_bf16<<<NDD / 2048, 256, 0, stream>>>(wk, wqkvB + NDD, NDD);
    cast_f32_bf16<<<NDD / 2048, 256, 0, stream>>>(wv, wqkvB + 2 * NDD, NDD);
    cast_f32_bf16<<<NDD / 2048, 256, 0, stream>>>(wo, woB, NDD);
    cast_f32_bf16<<<NDF / 2048, 256, 0, stream>>>(w1, w1B, NDF);
    cast_f32_bf16<<<NDF / 2048, 256, 0, stream>>>(w2, w2B, NDF);

    dim3 gQKV(QKVS / 128, NTOK / 128);    // (24, 32) = 768 blocks
    dim3 gD(D_MODEL / 128, NTOK / 128);   // (8, 32)  = 256 blocks
    dim3 gF(DFF / 128, NTOK / 128);       // (32, 32) = 1024 blocks
    dim3 gAttn(SEQ / 64, NH, BATCH);      // (32, 16, 2)

    // 1. h1 = LN(x, g1, be1)
    ln_kernel<<<NTOK, 64, 0, stream>>>(x, g1, be1, h1);
    // 2. qkv = h1 @ [wq;wk;wv]^T + [bq;bk;bv]   (fused, N=3072)
    gemm_bt<__bf16, false, true><<<gQKV, 256, 0, stream>>>(h1, wqkvB, bq, bk, bv, nullptr, qkv, NTOK, QKVS, D_MODEL);
    // 3. vt = transpose(v) per head
    transpose_v<<<gAttn, 256, 0, stream>>>(qkv, vt);
    // 4. ctx = softmax(q k^T / sqrt(dk)) v   (writes d_out)
    attn_kernel<<<gAttn, 256, 0, stream>>>(qkv, vt, ctx);
    // 5. x1 = x + ctx @ wo^T + bo   (fp32 trunk; h1 dead)
    gemm_bt<float, false, false><<<gD, 256, 0, stream>>>(ctx, woB, bo, bo, bo, x, x1, NTOK, D_MODEL, D_MODEL);
    // 6. h2 = LN(x1, g2, be2)   (overwrites ctx in d_out)
    ln_kernel<<<NTOK, 64, 0, stream>>>(x1, g2, be2, h2);
    // 7. ffh = gelu(h2 @ w1^T + b1)   (full 32 MiB over qkv+vt)
    gemm_bt<__bf16, true, false><<<gF, 256, 0, stream>>>(h2, w1B, b1, b1, b1, nullptr, ffh, NTOK, DFF, D_MODEL);
    // 8. out = x1 + ffh @ w2^T + b2   (overwrites h2/d_out; h2 fully consumed in 7)
    gemm_bt<float, false, false><<<gD, 256, 0, stream>>>(ffh, w2B, b2, b2, b2, x1, out, NTOK, D_MODEL, DFF);
}

// Round 2
// 487.307 us; speedup vs baseline: 1.4498x; 1.3045x over previous
//
#include <hip/hip_runtime.h>

typedef __attribute__((ext_vector_type(8))) __bf16 bf16x8;
typedef __attribute__((ext_vector_type(4))) __bf16 bf16x4;
typedef __attribute__((ext_vector_type(4))) float floatx4;
typedef void __attribute__((address_space(3))) lds_void_t;
typedef const void __attribute__((address_space(1))) gbl_void_t;

#define D_MODEL 1024
#define SEQ     2048
#define BATCH   2
#define NH      16
#define DK      64
#define DFF     4096
#define NTOK    (BATCH * SEQ)   // 4096
#define QKVS    3072            // fused qkv row stride

__device__ __forceinline__ float gelu_exact(float x) {
    return 0.5f * x * (1.0f + erff(x * 0.70710678118654752f));
}

// ---------------- fp32 -> bf16 weight cast, 8 elems/thread --------------------------
__global__ __launch_bounds__(256) void cast_f32_bf16(const float* __restrict__ src,
                                                     __bf16* __restrict__ dst, int n) {
    int i = (blockIdx.x * 256 + threadIdx.x) * 8;
    if (i >= n) return;
    floatx4 a = *(const floatx4*)(src + i);
    floatx4 b = *(const floatx4*)(src + i + 4);
    bf16x8 o;
    for (int j = 0; j < 4; ++j) { o[j] = (__bf16)a[j]; o[4 + j] = (__bf16)b[j]; }
    *(bf16x8*)(dst + i) = o;
}

// ---------------- LayerNorm: one wave per row of 1024; fp32 in, bf16 out ------------
__global__ __launch_bounds__(64) void ln_kernel(const float* __restrict__ x,
                                                const float* __restrict__ g,
                                                const float* __restrict__ b,
                                                __bf16* __restrict__ out) {
    int row = blockIdx.x, lane = threadIdx.x, base = lane * 16;
    const float* xr = x + (size_t)row * D_MODEL + base;
    float v[16];
    for (int j = 0; j < 4; ++j) {
        floatx4 a = *(const floatx4*)(xr + 4 * j);
        for (int i = 0; i < 4; ++i) v[4 * j + i] = a[i];
    }
    float s = 0.f, sq = 0.f;
    for (int i = 0; i < 16; ++i) { s += v[i]; sq += v[i] * v[i]; }
    for (int o = 1; o < 64; o <<= 1) { s += __shfl_xor(s, o); sq += __shfl_xor(sq, o); }
    float mu = s * (1.0f / D_MODEL);
    float var = sq * (1.0f / D_MODEL) - mu * mu;
    float rstd = rsqrtf(fmaxf(var, 0.f) + 1e-5f);

    const floatx4* gp = (const floatx4*)(g + base);
    const floatx4* bp = (const floatx4*)(b + base);
    bf16x8 o0, o1;
    for (int j = 0; j < 2; ++j) {
        floatx4 gv0 = gp[2 * j], gv1 = gp[2 * j + 1];
        floatx4 bv0 = bp[2 * j], bv1 = bp[2 * j + 1];
        for (int i = 0; i < 4; ++i) {
            float r0 = (v[8 * j + i] - mu) * rstd * gv0[i] + bv0[i];
            float r1 = (v[8 * j + 4 + i] - mu) * rstd * gv1[i] + bv1[i];
            if (j == 0) { o0[i] = (__bf16)r0; o0[4 + i] = (__bf16)r1; }
            else        { o1[i] = (__bf16)r0; o1[4 + i] = (__bf16)r1; }
        }
    }
    bf16x8* op = (bf16x8*)(out + (size_t)row * D_MODEL + base);
    op[0] = o0; op[1] = o1;
}

// ---------------- GEMM (m97-style): C = A@W^T + bias (+gelu) (+res) -----------------
// A, W bf16 K-contiguous. 128x128 tile, BK=32, 4 waves, global_load_lds width=16.
// TRIBIAS: bias segmented per 1024 cols (fused QKV).
template <typename OutT, bool GELU, bool TRIBIAS>
__global__ __launch_bounds__(256) void gemm_bt(const __bf16* __restrict__ A,
                                               const __bf16* __restrict__ W,
                                               const float* __restrict__ bias0,
                                               const float* __restrict__ bias1,
                                               const float* __restrict__ bias2,
                                               const float* __restrict__ res,
                                               OutT* __restrict__ out,
                                               int M, int N, int K) {
    __shared__ __bf16 As[128][32];
    __shared__ __bf16 Ws[128][32];

    int m0 = blockIdx.y * 128, n0 = blockIdx.x * 128;
    int t = threadIdx.x;
    int lane = t & 63, wave = t >> 6;
    int wm = (wave >> 1) * 64, wn = (wave & 1) * 64;
    int fr = lane & 15, quad = lane >> 4;
    int srow = t >> 2, scol = (t & 3) * 8;

    floatx4 acc[4][4] = {};

    const __bf16* Ab = A + (size_t)(m0 + srow) * K + scol;
    const __bf16* Wb = W + (size_t)(n0 + srow) * K + scol;
    lds_void_t* lA0 = (lds_void_t*)&As[wave * 16][0];
    lds_void_t* lA1 = (lds_void_t*)&As[64 + wave * 16][0];
    lds_void_t* lW0 = (lds_void_t*)&Ws[wave * 16][0];
    lds_void_t* lW1 = (lds_void_t*)&Ws[64 + wave * 16][0];

    for (int k0 = 0; k0 < K; k0 += 32) {
        __syncthreads();
        __builtin_amdgcn_global_load_lds((gbl_void_t*)(Ab + k0), lA0, 16, 0, 0);
        __builtin_amdgcn_global_load_lds((gbl_void_t*)(Ab + (size_t)64 * K + k0), lA1, 16, 0, 0);
        __builtin_amdgcn_global_load_lds((gbl_void_t*)(Wb + k0), lW0, 16, 0, 0);
        __builtin_amdgcn_global_load_lds((gbl_void_t*)(Wb + (size_t)64 * K + k0), lW1, 16, 0, 0);
        __syncthreads();

        bf16x8 af[4], wf[4];
        for (int i = 0; i < 4; ++i) af[i] = *(const bf16x8*)&As[wm + i * 16 + fr][quad * 8];
        for (int i = 0; i < 4; ++i) wf[i] = *(const bf16x8*)&Ws[wn + i * 16 + fr][quad * 8];
        for (int mi = 0; mi < 4; ++mi)
            for (int ni = 0; ni < 4; ++ni)
                acc[mi][ni] = __builtin_amdgcn_mfma_f32_16x16x32_bf16(af[mi], wf[ni], acc[mi][ni], 0, 0, 0);
    }

    for (int ni = 0; ni < 4; ++ni) {
        int col = n0 + wn + ni * 16 + fr;
        const float* bp = bias0;
        int bcol = col;
        if (TRIBIAS) { bp = col < 1024 ? bias0 : (col < 2048 ? bias1 : bias2); bcol = col & 1023; }
        float bv = bp[bcol];
        for (int mi = 0; mi < 4; ++mi) {
            for (int r = 0; r < 4; ++r) {
                int row = m0 + wm + mi * 16 + quad * 4 + r;
                float v = acc[mi][ni][r] + bv;
                if (GELU) v = gelu_exact(v);
                if (res) v += res[(size_t)row * N + col];
                out[(size_t)row * N + col] = (OutT)v;
            }
        }
    }
}

// ---------------- V transpose: qkv v-part [b][s][2048+h*64+d] -> vt[b][h][d][s] -----
__global__ __launch_bounds__(256) void transpose_v(const __bf16* __restrict__ qkv,
                                                   __bf16* __restrict__ vt) {
    __shared__ __bf16 tile[64][72];
    int b = blockIdx.z, h = blockIdx.y, s0 = blockIdx.x * 64;
    int t = threadIdx.x;
    int dl = (t & 7) * 8, sl = t >> 3;
    for (int p = 0; p < 2; ++p) {
        int s = sl + p * 32;
        bf16x8 val = *(const bf16x8*)(qkv + (size_t)(b * SEQ + s0 + s) * QKVS + 2048 + h * DK + dl);
        *(bf16x8*)&tile[s][dl] = val;
    }
    __syncthreads();
    int sl2 = (t & 7) * 8, d = t >> 3;
    for (int p = 0; p < 2; ++p) {
        int dd = d + p * 32;
        bf16x8 val;
        for (int j = 0; j < 8; ++j) val[j] = tile[sl2 + j][dd];
        *(bf16x8*)(vt + ((size_t)(b * NH + h) * DK + dd) * SEQ + s0 + sl2) = val;
    }
}

// ---------------- Flash attention, LDS-staged K/V, transposed-score layout ----------
// 1 wave = 16 q-rows, 128-key tiles. K (128x64) and V^T (64x128) tiles are staged
// ONCE per block into LDS via global_load_lds (4x less L2/LLC traffic than per-wave
// global reads), prefetched one tile ahead so LLC latency hides under compute.
// LDS rows are 128B/256B strides -> raw ds_read_b128 frags would be 16-way bank
// conflicts; fixed with XOR swizzle byte ^= ((row&7)<<4), applied BOTH-sides:
// linear LDS dest + inverse-swizzled GLOBAL source (global_load_lds can't scatter)
// + swizzled read offset. Residual 2-way aliasing is free.
// Per tile: ds_read all K/V frags -> barrier -> issue stage(t+1) -> QK MFMA ->
// softmax -> P via LDS -> PV MFMA -> barrier (drains vmcnt => next tile ready).
// launch_bounds(256,2): 256-VGPR budget so the ~200-reg frag set stays in regs.
__global__ __launch_bounds__(256, 2) void attn_kernel(const __bf16* __restrict__ qkv,
                                                      const __bf16* __restrict__ vt,
                                                      __bf16* __restrict__ ctx) {
    __shared__ __bf16 Klds[128][64];     // [key][d], cols XOR-swizzled in 16B granules
    __shared__ __bf16 Vlds[64][128];     // [d][key], cols XOR-swizzled
    __shared__ __bf16 Plds[4][16][136];  // [wave][query][128 keys + 8 pad]
    int b = blockIdx.z, h = blockIdx.y;
    int wave = threadIdx.x >> 6, lane = threadIdx.x & 63;
    int q0 = blockIdx.x * 64 + wave * 16;
    int fr = lane & 15, quad = lane >> 4;
    const float scale = 0.125f;   // 1/sqrt(64)

    // Q B-frag: B[n=fr(query)][k=quad*8+j(d)]
    const __bf16* qp = qkv + (size_t)(b * SEQ + q0 + fr) * QKVS + h * DK + quad * 8;
    bf16x8 qf0 = *(const bf16x8*)qp;
    bf16x8 qf1 = *(const bf16x8*)(qp + 32);

    const __bf16* kg = qkv + (size_t)b * SEQ * QKVS + 1024 + h * DK;  // + key*QKVS + d
    const __bf16* vg = vt + (size_t)(b * NH + h) * DK * SEQ;          // + d*SEQ + key

    // per-thread staging coords (linear LDS dest = lane*16; source pre-swizzled)
    int krow = wave * 8 + (lane >> 3);    // + p*32  (key row within tile)
    int kcbp = (lane & 7) * 16;           // physical col byte
    int vrow = wave * 4 + (lane >> 4);    // + p*16  (d row)
    int vcbp = (lane & 15) * 16;
    int swb = (fr & 7) << 4;              // read-side swizzle

    floatx4 o[4] = {};                 // C layout: row=query quad*4+r, col=d ti*16+fr
    float m_i = -1e30f, l_i = 0.f;     // per query fr (replicated over quads)

    // ---- prologue: stage tile 0 ----
#pragma unroll
    for (int p = 0; p < 4; ++p) {
        int kr = krow + p * 32;
        int vr = vrow + p * 16;
        __builtin_amdgcn_global_load_lds(
            (gbl_void_t*)(kg + (size_t)kr * QKVS + ((kcbp ^ ((kr & 7) << 4)) >> 1)),
            (lds_void_t*)&Klds[p * 32 + wave * 8][0], 16, 0, 0);
        __builtin_amdgcn_global_load_lds(
            (gbl_void_t*)(vg + (size_t)vr * SEQ + ((vcbp ^ ((vr & 7) << 4)) >> 1)),
            (lds_void_t*)&Vlds[p * 16 + wave * 4][0], 16, 0, 0);
    }
    __syncthreads();   // drains vmcnt -> tile 0 in LDS

    for (int k0 = 0; k0 < SEQ; k0 += 128) {
        // ---- batched LDS->reg frag reads (must complete before re-staging) ----
        bf16x8 kA[8], kB[8];
#pragma unroll
        for (int f = 0; f < 8; ++f) {
            const char* rp = (const char*)&Klds[0][0] + (f * 16 + fr) * 128;
            kA[f] = *(const bf16x8*)(rp + ((quad * 16) ^ swb));
            kB[f] = *(const bf16x8*)(rp + ((64 + quad * 16) ^ swb));
        }
        bf16x8 vf[4][4];
#pragma unroll
        for (int c = 0; c < 4; ++c)
#pragma unroll
            for (int ti = 0; ti < 4; ++ti)
                vf[c][ti] = *(const bf16x8*)((const char*)&Vlds[0][0] +
                                             (ti * 16 + fr) * 256 + ((c * 64 + quad * 16) ^ swb));
        __syncthreads();   // all waves done reading K/V LDS (lgkm drained)

        // ---- issue next tile's stage; latency hides under compute below ----
        if (k0 + 128 < SEQ) {
#pragma unroll
            for (int p = 0; p < 4; ++p) {
                int kr = krow + p * 32;
                int vr = vrow + p * 16;
                __builtin_amdgcn_global_load_lds(
                    (gbl_void_t*)(kg + (size_t)(k0 + 128 + kr) * QKVS + ((kcbp ^ ((kr & 7) << 4)) >> 1)),
                    (lds_void_t*)&Klds[p * 32 + wave * 8][0], 16, 0, 0);
                __builtin_amdgcn_global_load_lds(
                    (gbl_void_t*)(vg + (size_t)vr * SEQ + k0 + 128 + ((vcbp ^ ((vr & 7) << 4)) >> 1)),
                    (lds_void_t*)&Vlds[p * 16 + wave * 4][0], 16, 0, 0);
            }
        }

        // ---- QK^T MFMA cluster ----
        floatx4 s[8];
#pragma unroll
        for (int f = 0; f < 8; ++f) {
            floatx4 z = {0.f, 0.f, 0.f, 0.f};
            z = __builtin_amdgcn_mfma_f32_16x16x32_bf16(kA[f], qf0, z, 0, 0, 0);
            s[f] = __builtin_amdgcn_mfma_f32_16x16x32_bf16(kB[f], qf1, z, 0, 0, 0);
        }

        // ---- online softmax for query fr: local tree + 2 chained shfls ----
        float mx = s[0][0];
#pragma unroll
        for (int f = 0; f < 8; ++f)
#pragma unroll
            for (int r = 0; r < 4; ++r) mx = fmaxf(mx, s[f][r]);
        mx *= scale;
        mx = fmaxf(mx, __shfl_xor(mx, 16));
        mx = fmaxf(mx, __shfl_xor(mx, 32));
        float mn = fmaxf(m_i, mx);
        float alpha = __expf(m_i - mn);
        m_i = mn;
        float rs = 0.f;
#pragma unroll
        for (int f = 0; f < 8; ++f) {
            bf16x4 pk;
#pragma unroll
            for (int r = 0; r < 4; ++r) {
                float p = __expf(s[f][r] * scale - mn);
                rs += p;
                pk[r] = (__bf16)p;
            }
            *(bf16x4*)&Plds[wave][fr][f * 16 + quad * 4] = pk;   // ds_write_b64
        }
        rs += __shfl_xor(rs, 16);
        rs += __shfl_xor(rs, 32);
        l_i = l_i * alpha + rs;
        // broadcast alpha to o-layout lanes (query quad*4+r held by lane quad*4+r)
        float aB[4];
#pragma unroll
        for (int r = 0; r < 4; ++r) aB[r] = __shfl(alpha, quad * 4 + r);
#pragma unroll
        for (int ti = 0; ti < 4; ++ti)
#pragma unroll
            for (int r = 0; r < 4; ++r) o[ti][r] *= aB[r];
        __threadfence_block();   // order wave-private LDS writes -> cross-lane reads

        // ---- PV: batch the 4 P ds_read_b128, then pure MFMA cluster ----
        bf16x8 pa[4];
#pragma unroll
        for (int c = 0; c < 4; ++c)
            pa[c] = *(const bf16x8*)&Plds[wave][fr][c * 32 + quad * 8];
#pragma unroll
        for (int c = 0; c < 4; ++c)
#pragma unroll
            for (int ti = 0; ti < 4; ++ti)
                o[ti] = __builtin_amdgcn_mfma_f32_16x16x32_bf16(pa[c], vf[c][ti], o[ti], 0, 0, 0);
        __threadfence_block();   // P reads done before next iteration's writes

        __syncthreads();   // drains vmcnt(0) -> staged tile t+1 ready in LDS
    }
    float lB[4];
#pragma unroll
    for (int r = 0; r < 4; ++r) lB[r] = __shfl(l_i, quad * 4 + r);
#pragma unroll
    for (int ti = 0; ti < 4; ++ti)
#pragma unroll
        for (int r = 0; r < 4; ++r)
            ctx[(size_t)(b * SEQ + q0 + quad * 4 + r) * D_MODEL + h * DK + ti * 16 + fr] =
                (__bf16)(o[ti][r] / lB[r]);
}

// -----------------------------------------------------------------------------------
// Inputs fp32, output fp32. Workspace exactly 72 MiB:
//   [0,6M):   wqkvB (wq,wk,wv adjacent -> one [3072][1024] matrix)
//   [6,8M):   woB      [8,16M): w1B      [16,24M): w2B
//   [24,40M): h1 (dead after qkv-gemm) -> x1 fp32 trunk
//   [40,64M): qkv [4096][3072]  -> (dead after attn) ffh lower part
//   [64,72M): vt                -> (dead after attn) ffh upper part; ffh = [40,72M)
//   d_out:    ctx -> h2 -> final out
extern "C" void kernel_launch(void* const* d_in, const int* in_sizes, int n_in,
                              void* d_out, int out_size, void* d_ws, size_t ws_size,
                              hipStream_t stream) {
    const float* x   = (const float*)d_in[0];
    const float* wq  = (const float*)d_in[1];
    const float* bq  = (const float*)d_in[2];
    const float* wk  = (const float*)d_in[3];
    const float* bk  = (const float*)d_in[4];
    const float* wv  = (const float*)d_in[5];
    const float* bv  = (const float*)d_in[6];
    const float* wo  = (const float*)d_in[7];
    const float* bo  = (const float*)d_in[8];
    const float* w1  = (const float*)d_in[9];
    const float* b1  = (const float*)d_in[10];
    const float* w2  = (const float*)d_in[11];
    const float* b2  = (const float*)d_in[12];
    const float* g1  = (const float*)d_in[13];
    const float* be1 = (const float*)d_in[14];
    const float* g2  = (const float*)d_in[15];
    const float* be2 = (const float*)d_in[16];
    float* out = (float*)d_out;

    char* ws = (char*)d_ws;
    const size_t MB = 1024 * 1024;
    __bf16* wqkvB = (__bf16*)(ws);                 // [0,6M)
    __bf16* woB   = (__bf16*)(ws + 6 * MB);
    __bf16* w1B   = (__bf16*)(ws + 8 * MB);
    __bf16* w2B   = (__bf16*)(ws + 16 * MB);
    __bf16* h1    = (__bf16*)(ws + 24 * MB);       // dead after qkv-gemm
    float*  x1    = (float*)(ws + 24 * MB);        // fp32 trunk [24,40M)
    __bf16* qkv   = (__bf16*)(ws + 40 * MB);       // [40,64M)
    __bf16* vt    = (__bf16*)(ws + 64 * MB);       // [64,72M)
    __bf16* ffh   = (__bf16*)(ws + 40 * MB);       // [40,72M) after qkv+vt die
    __bf16* ctx   = (__bf16*)d_out;                // d_out scratch [0,8M)
    __bf16* h2    = (__bf16*)d_out;                // d_out scratch (after ctx dies)

    const int NDD = D_MODEL * D_MODEL;   // 1M
    const int NDF = D_MODEL * DFF;       // 4M
    cast_f32_bf16<<<NDD / 2048, 256, 0, stream>>>(wq, wqkvB, NDD);
    cast_f32_bf16<<<NDD / 2048, 256, 0, stream>>>(wk, wqkvB + NDD, NDD);
    cast_f32_bf16<<<NDD / 2048, 256, 0, stream>>>(wv, wqkvB + 2 * NDD, NDD);
    cast_f32_bf16<<<NDD / 2048, 256, 0, stream>>>(wo, woB, NDD);
    cast_f32_bf16<<<NDF / 2048, 256, 0, stream>>>(w1, w1B, NDF);
    cast_f32_bf16<<<NDF / 2048, 256, 0, stream>>>(w2, w2B, NDF);

    dim3 gQKV(QKVS / 128, NTOK / 128);    // (24, 32) = 768 blocks
    dim3 gD(D_MODEL / 128, NTOK / 128);   // (8, 32)  = 256 blocks
    dim3 gF(DFF / 128, NTOK / 128);       // (32, 32) = 1024 blocks
    dim3 gAttn(SEQ / 64, NH, BATCH);      // (32, 16, 2)

    // 1. h1 = LN(x, g1, be1)
    ln_kernel<<<NTOK, 64, 0, stream>>>(x, g1, be1, h1);
    // 2. qkv = h1 @ [wq;wk;wv]^T + [bq;bk;bv]   (fused, N=3072)
    gemm_bt<__bf16, false, true><<<gQKV, 256, 0, stream>>>(h1, wqkvB, bq, bk, bv, nullptr, qkv, NTOK, QKVS, D_MODEL);
    // 3. vt = transpose(v) per head
    transpose_v<<<gAttn, 256, 0, stream>>>(qkv, vt);
    // 4. ctx = softmax(q k^T / sqrt(dk)) v   (writes d_out)
    attn_kernel<<<gAttn, 256, 0, stream>>>(qkv, vt, ctx);
    // 5. x1 = x + ctx @ wo^T + bo   (fp32 trunk; h1 dead)
    gemm_bt<float, false, false><<<gD, 256, 0, stream>>>(ctx, woB, bo, bo, bo, x, x1, NTOK, D_MODEL, D_MODEL);
    // 6. h2 = LN(x1, g2, be2)   (overwrites ctx in d_out)
    ln_kernel<<<NTOK, 64, 0, stream>>>(x1, g2, be2, h2);
    // 7. ffh = gelu(h2 @ w1^T + b1)   (full 32 MiB over qkv+vt)
    gemm_bt<__bf16, true, false><<<gF, 256, 0, stream>>>(h2, w1B, b1, b1, b1, nullptr, ffh, NTOK, DFF, D_MODEL);
    // 8. out = x1 + ffh @ w2^T + b2   (overwrites h2/d_out; h2 fully consumed in 7)
    gemm_bt<float, false, false><<<gD, 256, 0, stream>>>(ffh, w2B, b2, b2, b2, x1, out, NTOK, D_MODEL, DFF);
}

// Round 3
// 432.493 us; speedup vs baseline: 1.6336x; 1.1267x over previous
//
#include <hip/hip_runtime.h>

typedef __attribute__((ext_vector_type(8))) __bf16 bf16x8;
typedef __attribute__((ext_vector_type(4))) __bf16 bf16x4;
typedef __attribute__((ext_vector_type(4))) float floatx4;
typedef void __attribute__((address_space(3))) lds_void_t;
typedef const void __attribute__((address_space(1))) gbl_void_t;

#define D_MODEL 1024
#define SEQ     2048
#define BATCH   2
#define NH      16
#define DK      64
#define DFF     4096
#define NTOK    (BATCH * SEQ)   // 4096
#define QKVS    3072            // fused qkv row stride

__device__ __forceinline__ float gelu_exact(float x) {
    return 0.5f * x * (1.0f + erff(x * 0.70710678118654752f));
}

// ---------------- fp32 -> bf16 weight cast, 8 elems/thread --------------------------
__global__ __launch_bounds__(256) void cast_f32_bf16(const float* __restrict__ src,
                                                     __bf16* __restrict__ dst, int n) {
    int i = (blockIdx.x * 256 + threadIdx.x) * 8;
    if (i >= n) return;
    floatx4 a = *(const floatx4*)(src + i);
    floatx4 b = *(const floatx4*)(src + i + 4);
    bf16x8 o;
    for (int j = 0; j < 4; ++j) { o[j] = (__bf16)a[j]; o[4 + j] = (__bf16)b[j]; }
    *(bf16x8*)(dst + i) = o;
}

// ---------------- LayerNorm: one wave per row of 1024; fp32 in, bf16 out ------------
__global__ __launch_bounds__(64) void ln_kernel(const float* __restrict__ x,
                                                const float* __restrict__ g,
                                                const float* __restrict__ b,
                                                __bf16* __restrict__ out) {
    int row = blockIdx.x, lane = threadIdx.x, base = lane * 16;
    const float* xr = x + (size_t)row * D_MODEL + base;
    float v[16];
    for (int j = 0; j < 4; ++j) {
        floatx4 a = *(const floatx4*)(xr + 4 * j);
        for (int i = 0; i < 4; ++i) v[4 * j + i] = a[i];
    }
    float s = 0.f, sq = 0.f;
    for (int i = 0; i < 16; ++i) { s += v[i]; sq += v[i] * v[i]; }
    for (int o = 1; o < 64; o <<= 1) { s += __shfl_xor(s, o); sq += __shfl_xor(sq, o); }
    float mu = s * (1.0f / D_MODEL);
    float var = sq * (1.0f / D_MODEL) - mu * mu;
    float rstd = rsqrtf(fmaxf(var, 0.f) + 1e-5f);

    const floatx4* gp = (const floatx4*)(g + base);
    const floatx4* bp = (const floatx4*)(b + base);
    bf16x8 o0, o1;
    for (int j = 0; j < 2; ++j) {
        floatx4 gv0 = gp[2 * j], gv1 = gp[2 * j + 1];
        floatx4 bv0 = bp[2 * j], bv1 = bp[2 * j + 1];
        for (int i = 0; i < 4; ++i) {
            float r0 = (v[8 * j + i] - mu) * rstd * gv0[i] + bv0[i];
            float r1 = (v[8 * j + 4 + i] - mu) * rstd * gv1[i] + bv1[i];
            if (j == 0) { o0[i] = (__bf16)r0; o0[4 + i] = (__bf16)r1; }
            else        { o1[i] = (__bf16)r0; o1[4 + i] = (__bf16)r1; }
        }
    }
    bf16x8* op = (bf16x8*)(out + (size_t)row * D_MODEL + base);
    op[0] = o0; op[1] = o1;
}

// ---------------- GEMM: C = A@W^T + bias (+gelu) (+res), 2-phase prefetch -----------
// A, W bf16 K-contiguous. 128x128 tile, BK=32, 4 waves, global_load_lds width=16.
// Double-buffered LDS, stage(k+1) issued right after the barrier so its latency
// hides under the K-step's ds_read+MFMA; ONE barrier per K-step (T3-minimum).
// KSPLIT>1: blockIdx.z takes a K-slice, raw fp32 partial -> out (z=0) / part1 (z=1);
// bias/res/gelu applied by reduce_k2 afterwards.
template <typename OutT, bool GELU, bool TRIBIAS, int KSPLIT>
__global__ __launch_bounds__(256) void gemm_bt(const __bf16* __restrict__ A,
                                               const __bf16* __restrict__ W,
                                               const float* __restrict__ bias0,
                                               const float* __restrict__ bias1,
                                               const float* __restrict__ bias2,
                                               const float* __restrict__ res,
                                               OutT* out, float* part1,
                                               int M, int N, int K) {
    __shared__ __bf16 As[2][128][32];
    __shared__ __bf16 Ws[2][128][32];

    int m0 = blockIdx.y * 128, n0 = blockIdx.x * 128;
    int t = threadIdx.x;
    int lane = t & 63, wave = t >> 6;
    int wm = (wave >> 1) * 64, wn = (wave & 1) * 64;
    int fr = lane & 15, quad = lane >> 4;
    int srow = t >> 2, scol = (t & 3) * 8;

    int Ks = K / KSPLIT;
    int kbeg = (KSPLIT > 1) ? blockIdx.z * Ks : 0;

    floatx4 acc[4][4] = {};

    const __bf16* Ab = A + (size_t)(m0 + srow) * K + kbeg + scol;
    const __bf16* Wb = W + (size_t)(n0 + srow) * K + kbeg + scol;

    auto stage = [&](int buf, int k0) {
        __builtin_amdgcn_global_load_lds((gbl_void_t*)(Ab + k0),
                                         (lds_void_t*)&As[buf][wave * 16][0], 16, 0, 0);
        __builtin_amdgcn_global_load_lds((gbl_void_t*)(Ab + (size_t)64 * K + k0),
                                         (lds_void_t*)&As[buf][64 + wave * 16][0], 16, 0, 0);
        __builtin_amdgcn_global_load_lds((gbl_void_t*)(Wb + k0),
                                         (lds_void_t*)&Ws[buf][wave * 16][0], 16, 0, 0);
        __builtin_amdgcn_global_load_lds((gbl_void_t*)(Wb + (size_t)64 * K + k0),
                                         (lds_void_t*)&Ws[buf][64 + wave * 16][0], 16, 0, 0);
    };

    stage(0, 0);
    int nsteps = Ks / 32;
    for (int s = 0; s < nsteps; ++s) {
        int cur = s & 1;
        __syncthreads();   // buf[cur] staged (vmcnt drained) + prior reads done
        if (s + 1 < nsteps) stage(cur ^ 1, (s + 1) * 32);

        bf16x8 af[4], wf[4];
#pragma unroll
        for (int i = 0; i < 4; ++i) af[i] = *(const bf16x8*)&As[cur][wm + i * 16 + fr][quad * 8];
#pragma unroll
        for (int i = 0; i < 4; ++i) wf[i] = *(const bf16x8*)&Ws[cur][wn + i * 16 + fr][quad * 8];
#pragma unroll
        for (int mi = 0; mi < 4; ++mi)
#pragma unroll
            for (int ni = 0; ni < 4; ++ni)
                acc[mi][ni] = __builtin_amdgcn_mfma_f32_16x16x32_bf16(af[mi], wf[ni], acc[mi][ni], 0, 0, 0);
    }

    if (KSPLIT > 1) {
        float* pb = (blockIdx.z == 0) ? (float*)out : part1;
#pragma unroll
        for (int ni = 0; ni < 4; ++ni) {
            int col = n0 + wn + ni * 16 + fr;
#pragma unroll
            for (int mi = 0; mi < 4; ++mi)
#pragma unroll
                for (int r = 0; r < 4; ++r) {
                    int row = m0 + wm + mi * 16 + quad * 4 + r;
                    pb[(size_t)row * N + col] = acc[mi][ni][r];
                }
        }
    } else {
#pragma unroll
        for (int ni = 0; ni < 4; ++ni) {
            int col = n0 + wn + ni * 16 + fr;
            const float* bp = bias0;
            int bcol = col;
            if (TRIBIAS) { bp = col < 1024 ? bias0 : (col < 2048 ? bias1 : bias2); bcol = col & 1023; }
            float bv = bp[bcol];
#pragma unroll
            for (int mi = 0; mi < 4; ++mi) {
#pragma unroll
                for (int r = 0; r < 4; ++r) {
                    int row = m0 + wm + mi * 16 + quad * 4 + r;
                    float v = acc[mi][ni][r] + bv;
                    if (GELU) v = gelu_exact(v);
                    if (res) v += res[(size_t)row * N + col];
                    out[(size_t)row * N + col] = (OutT)v;
                }
            }
        }
    }
}

// ---------------- split-K reduce: out = p0 + p1 + res + bias (N=1024 pow2) ----------
__global__ __launch_bounds__(256) void reduce_k2(const float* __restrict__ p0,
                                                 const float* p1,
                                                 const float* __restrict__ res,
                                                 const float* __restrict__ bias,
                                                 float* out) {
    int i = (blockIdx.x * 256 + threadIdx.x) * 4;
    floatx4 a = *(const floatx4*)(p0 + i);
    floatx4 b = *(const floatx4*)(p1 + i);
    floatx4 r = *(const floatx4*)(res + i);
    floatx4 bv = *(const floatx4*)(bias + (i & 1023));
    floatx4 o;
#pragma unroll
    for (int j = 0; j < 4; ++j) o[j] = a[j] + b[j] + r[j] + bv[j];
    *(floatx4*)(out + i) = o;
}

// ---------------- V transpose: qkv v-part [b][s][2048+h*64+d] -> vt[b][h][d][s] -----
__global__ __launch_bounds__(256) void transpose_v(const __bf16* __restrict__ qkv,
                                                   __bf16* __restrict__ vt) {
    __shared__ __bf16 tile[64][72];
    int b = blockIdx.z, h = blockIdx.y, s0 = blockIdx.x * 64;
    int t = threadIdx.x;
    int dl = (t & 7) * 8, sl = t >> 3;
    for (int p = 0; p < 2; ++p) {
        int s = sl + p * 32;
        bf16x8 val = *(const bf16x8*)(qkv + (size_t)(b * SEQ + s0 + s) * QKVS + 2048 + h * DK + dl);
        *(bf16x8*)&tile[s][dl] = val;
    }
    __syncthreads();
    int sl2 = (t & 7) * 8, d = t >> 3;
    for (int p = 0; p < 2; ++p) {
        int dd = d + p * 32;
        bf16x8 val;
        for (int j = 0; j < 8; ++j) val[j] = tile[sl2 + j][dd];
        *(bf16x8*)(vt + ((size_t)(b * NH + h) * DK + dd) * SEQ + s0 + sl2) = val;
    }
}

// ---------------- Flash attention, LDS-staged K/V, transposed-score layout ----------
// (unchanged from round 2 -- it left the top-5)
__global__ __launch_bounds__(256, 2) void attn_kernel(const __bf16* __restrict__ qkv,
                                                      const __bf16* __restrict__ vt,
                                                      __bf16* __restrict__ ctx) {
    __shared__ __bf16 Klds[128][64];     // [key][d], cols XOR-swizzled in 16B granules
    __shared__ __bf16 Vlds[64][128];     // [d][key], cols XOR-swizzled
    __shared__ __bf16 Plds[4][16][136];  // [wave][query][128 keys + 8 pad]
    int b = blockIdx.z, h = blockIdx.y;
    int wave = threadIdx.x >> 6, lane = threadIdx.x & 63;
    int q0 = blockIdx.x * 64 + wave * 16;
    int fr = lane & 15, quad = lane >> 4;
    const float scale = 0.125f;   // 1/sqrt(64)

    const __bf16* qp = qkv + (size_t)(b * SEQ + q0 + fr) * QKVS + h * DK + quad * 8;
    bf16x8 qf0 = *(const bf16x8*)qp;
    bf16x8 qf1 = *(const bf16x8*)(qp + 32);

    const __bf16* kg = qkv + (size_t)b * SEQ * QKVS + 1024 + h * DK;  // + key*QKVS + d
    const __bf16* vg = vt + (size_t)(b * NH + h) * DK * SEQ;          // + d*SEQ + key

    int krow = wave * 8 + (lane >> 3);    // + p*32  (key row within tile)
    int kcbp = (lane & 7) * 16;           // physical col byte
    int vrow = wave * 4 + (lane >> 4);    // + p*16  (d row)
    int vcbp = (lane & 15) * 16;
    int swb = (fr & 7) << 4;              // read-side swizzle

    floatx4 o[4] = {};
    float m_i = -1e30f, l_i = 0.f;

#pragma unroll
    for (int p = 0; p < 4; ++p) {
        int kr = krow + p * 32;
        int vr = vrow + p * 16;
        __builtin_amdgcn_global_load_lds(
            (gbl_void_t*)(kg + (size_t)kr * QKVS + ((kcbp ^ ((kr & 7) << 4)) >> 1)),
            (lds_void_t*)&Klds[p * 32 + wave * 8][0], 16, 0, 0);
        __builtin_amdgcn_global_load_lds(
            (gbl_void_t*)(vg + (size_t)vr * SEQ + ((vcbp ^ ((vr & 7) << 4)) >> 1)),
            (lds_void_t*)&Vlds[p * 16 + wave * 4][0], 16, 0, 0);
    }
    __syncthreads();

    for (int k0 = 0; k0 < SEQ; k0 += 128) {
        bf16x8 kA[8], kB[8];
#pragma unroll
        for (int f = 0; f < 8; ++f) {
            const char* rp = (const char*)&Klds[0][0] + (f * 16 + fr) * 128;
            kA[f] = *(const bf16x8*)(rp + ((quad * 16) ^ swb));
            kB[f] = *(const bf16x8*)(rp + ((64 + quad * 16) ^ swb));
        }
        bf16x8 vf[4][4];
#pragma unroll
        for (int c = 0; c < 4; ++c)
#pragma unroll
            for (int ti = 0; ti < 4; ++ti)
                vf[c][ti] = *(const bf16x8*)((const char*)&Vlds[0][0] +
                                             (ti * 16 + fr) * 256 + ((c * 64 + quad * 16) ^ swb));
        __syncthreads();

        if (k0 + 128 < SEQ) {
#pragma unroll
            for (int p = 0; p < 4; ++p) {
                int kr = krow + p * 32;
                int vr = vrow + p * 16;
                __builtin_amdgcn_global_load_lds(
                    (gbl_void_t*)(kg + (size_t)(k0 + 128 + kr) * QKVS + ((kcbp ^ ((kr & 7) << 4)) >> 1)),
                    (lds_void_t*)&Klds[p * 32 + wave * 8][0], 16, 0, 0);
                __builtin_amdgcn_global_load_lds(
                    (gbl_void_t*)(vg + (size_t)vr * SEQ + k0 + 128 + ((vcbp ^ ((vr & 7) << 4)) >> 1)),
                    (lds_void_t*)&Vlds[p * 16 + wave * 4][0], 16, 0, 0);
            }
        }

        floatx4 s[8];
#pragma unroll
        for (int f = 0; f < 8; ++f) {
            floatx4 z = {0.f, 0.f, 0.f, 0.f};
            z = __builtin_amdgcn_mfma_f32_16x16x32_bf16(kA[f], qf0, z, 0, 0, 0);
            s[f] = __builtin_amdgcn_mfma_f32_16x16x32_bf16(kB[f], qf1, z, 0, 0, 0);
        }

        float mx = s[0][0];
#pragma unroll
        for (int f = 0; f < 8; ++f)
#pragma unroll
            for (int r = 0; r < 4; ++r) mx = fmaxf(mx, s[f][r]);
        mx *= scale;
        mx = fmaxf(mx, __shfl_xor(mx, 16));
        mx = fmaxf(mx, __shfl_xor(mx, 32));
        float mn = fmaxf(m_i, mx);
        float alpha = __expf(m_i - mn);
        m_i = mn;
        float rs = 0.f;
#pragma unroll
        for (int f = 0; f < 8; ++f) {
            bf16x4 pk;
#pragma unroll
            for (int r = 0; r < 4; ++r) {
                float p = __expf(s[f][r] * scale - mn);
                rs += p;
                pk[r] = (__bf16)p;
            }
            *(bf16x4*)&Plds[wave][fr][f * 16 + quad * 4] = pk;
        }
        rs += __shfl_xor(rs, 16);
        rs += __shfl_xor(rs, 32);
        l_i = l_i * alpha + rs;
        float aB[4];
#pragma unroll
        for (int r = 0; r < 4; ++r) aB[r] = __shfl(alpha, quad * 4 + r);
#pragma unroll
        for (int ti = 0; ti < 4; ++ti)
#pragma unroll
            for (int r = 0; r < 4; ++r) o[ti][r] *= aB[r];
        __threadfence_block();

        bf16x8 pa[4];
#pragma unroll
        for (int c = 0; c < 4; ++c)
            pa[c] = *(const bf16x8*)&Plds[wave][fr][c * 32 + quad * 8];
#pragma unroll
        for (int c = 0; c < 4; ++c)
#pragma unroll
            for (int ti = 0; ti < 4; ++ti)
                o[ti] = __builtin_amdgcn_mfma_f32_16x16x32_bf16(pa[c], vf[c][ti], o[ti], 0, 0, 0);
        __threadfence_block();

        __syncthreads();
    }
    float lB[4];
#pragma unroll
    for (int r = 0; r < 4; ++r) lB[r] = __shfl(l_i, quad * 4 + r);
#pragma unroll
    for (int ti = 0; ti < 4; ++ti)
#pragma unroll
        for (int r = 0; r < 4; ++r)
            ctx[(size_t)(b * SEQ + q0 + quad * 4 + r) * D_MODEL + h * DK + ti * 16 + fr] =
                (__bf16)(o[ti][r] / lB[r]);
}

// -----------------------------------------------------------------------------------
// Workspace 72 MiB:
//   [0,6M):   wqkvB    [6,8M): woB    [8,16M): w1B    [16,24M): w2B
//   [24,40M): h1 -> x1 fp32 trunk
//   [40,64M): qkv      [64,72M): vt
//   AO split-K partials:  [40,56M) + [56,72M)  (qkv/vt dead after attn)
//   ffh = [40,72M) after AO reduce
//   FF2 split-K partials: [0,16M) (wqkvB/woB/w1B dead) + d_out (h2 dead)
//   d_out:    ctx -> h2 -> FF2 partial1 -> final out
extern "C" void kernel_launch(void* const* d_in, const int* in_sizes, int n_in,
                              void* d_out, int out_size, void* d_ws, size_t ws_size,
                              hipStream_t stream) {
    const float* x   = (const float*)d_in[0];
    const float* wq  = (const float*)d_in[1];
    const float* bq  = (const float*)d_in[2];
    const float* wk  = (const float*)d_in[3];
    const float* bk  = (const float*)d_in[4];
    const float* wv  = (const float*)d_in[5];
    const float* bv  = (const float*)d_in[6];
    const float* wo  = (const float*)d_in[7];
    const float* bo  = (const float*)d_in[8];
    const float* w1  = (const float*)d_in[9];
    const float* b1  = (const float*)d_in[10];
    const float* w2  = (const float*)d_in[11];
    const float* b2  = (const float*)d_in[12];
    const float* g1  = (const float*)d_in[13];
    const float* be1 = (const float*)d_in[14];
    const float* g2  = (const float*)d_in[15];
    const float* be2 = (const float*)d_in[16];
    float* out = (float*)d_out;

    char* ws = (char*)d_ws;
    const size_t MB = 1024 * 1024;
    __bf16* wqkvB = (__bf16*)(ws);                 // [0,6M)
    __bf16* woB   = (__bf16*)(ws + 6 * MB);
    __bf16* w1B   = (__bf16*)(ws + 8 * MB);
    __bf16* w2B   = (__bf16*)(ws + 16 * MB);
    __bf16* h1    = (__bf16*)(ws + 24 * MB);       // dead after qkv-gemm
    float*  x1    = (float*)(ws + 24 * MB);        // fp32 trunk [24,40M)
    __bf16* qkv   = (__bf16*)(ws + 40 * MB);       // [40,64M)
    __bf16* vt    = (__bf16*)(ws + 64 * MB);       // [64,72M)
    __bf16* ffh   = (__bf16*)(ws + 40 * MB);       // [40,72M) after qkv+vt die
    float*  pA0   = (float*)(ws + 40 * MB);        // AO partial z=0
    float*  pA1   = (float*)(ws + 56 * MB);        // AO partial z=1
    float*  pF0   = (float*)(ws);                  // FF2 partial z=0 [0,16M)
    __bf16* ctx   = (__bf16*)d_out;                // d_out scratch [0,8M)
    __bf16* h2    = (__bf16*)d_out;                // d_out scratch (after ctx dies)

    const int NDD = D_MODEL * D_MODEL;   // 1M
    const int NDF = D_MODEL * DFF;       // 4M
    cast_f32_bf16<<<NDD / 2048, 256, 0, stream>>>(wq, wqkvB, NDD);
    cast_f32_bf16<<<NDD / 2048, 256, 0, stream>>>(wk, wqkvB + NDD, NDD);
    cast_f32_bf16<<<NDD / 2048, 256, 0, stream>>>(wv, wqkvB + 2 * NDD, NDD);
    cast_f32_bf16<<<NDD / 2048, 256, 0, stream>>>(wo, woB, NDD);
    cast_f32_bf16<<<NDF / 2048, 256, 0, stream>>>(w1, w1B, NDF);
    cast_f32_bf16<<<NDF / 2048, 256, 0, stream>>>(w2, w2B, NDF);

    dim3 gQKV(QKVS / 128, NTOK / 128);       // (24, 32) = 768 blocks
    dim3 gDz(D_MODEL / 128, NTOK / 128, 2);  // (8, 32, 2) = 512 blocks, split-K=2
    dim3 gF(DFF / 128, NTOK / 128);          // (32, 32) = 1024 blocks
    dim3 gAttn(SEQ / 64, NH, BATCH);         // (32, 16, 2)
    int gRed = NTOK * D_MODEL / (256 * 4);   // 4096 blocks

    // 1. h1 = LN(x, g1, be1)
    ln_kernel<<<NTOK, 64, 0, stream>>>(x, g1, be1, h1);
    // 2. qkv = h1 @ [wq;wk;wv]^T + [bq;bk;bv]   (fused, N=3072)
    gemm_bt<__bf16, false, true, 1><<<gQKV, 256, 0, stream>>>(h1, wqkvB, bq, bk, bv, nullptr, qkv, nullptr, NTOK, QKVS, D_MODEL);
    // 3. vt = transpose(v) per head
    transpose_v<<<gAttn, 256, 0, stream>>>(qkv, vt);
    // 4. ctx = softmax(q k^T / sqrt(dk)) v   (writes d_out)
    attn_kernel<<<gAttn, 256, 0, stream>>>(qkv, vt, ctx);
    // 5. x1 = x + ctx @ wo^T + bo   (split-K=2: partials over dead qkv/vt, then reduce)
    gemm_bt<float, false, false, 2><<<gDz, 256, 0, stream>>>(ctx, woB, nullptr, nullptr, nullptr, nullptr, pA0, pA1, NTOK, D_MODEL, D_MODEL);
    reduce_k2<<<gRed, 256, 0, stream>>>(pA0, pA1, x, bo, x1);
    // 6. h2 = LN(x1, g2, be2)   (d_out scratch)
    ln_kernel<<<NTOK, 64, 0, stream>>>(x1, g2, be2, h2);
    // 7. ffh = gelu(h2 @ w1^T + b1)   (full 32 MiB over qkv+vt)
    gemm_bt<__bf16, true, false, 1><<<gF, 256, 0, stream>>>(h2, w1B, b1, b1, b1, nullptr, ffh, nullptr, NTOK, DFF, D_MODEL);
    // 8. out = x1 + ffh @ w2^T + b2   (split-K=2: p0=[0,16M), p1=d_out, reduce in place)
    gemm_bt<float, false, false, 2><<<gDz, 256, 0, stream>>>(ffh, w2B, nullptr, nullptr, nullptr, nullptr, pF0, (float*)d_out, NTOK, D_MODEL, DFF);
    reduce_k2<<<gRed, 256, 0, stream>>>(pF0, (float*)d_out, x1, b2, out);
}

// Round 4
// 432.313 us; speedup vs baseline: 1.6343x; 1.0004x over previous
//
#include <hip/hip_runtime.h>

typedef __attribute__((ext_vector_type(8))) __bf16 bf16x8;
typedef __attribute__((ext_vector_type(4))) __bf16 bf16x4;
typedef __attribute__((ext_vector_type(4))) float floatx4;
typedef void __attribute__((address_space(3))) lds_void_t;
typedef const void __attribute__((address_space(1))) gbl_void_t;

#define D_MODEL 1024
#define SEQ     2048
#define BATCH   2
#define NH      16
#define DK      64
#define DFF     4096
#define NTOK    (BATCH * SEQ)   // 4096
#define QKVS    3072            // fused qkv row stride

#if __has_builtin(__builtin_amdgcn_exp2f)
#define EXP2(x) __builtin_amdgcn_exp2f(x)
#else
#define EXP2(x) exp2f(x)
#endif

__device__ __forceinline__ float gelu_exact(float x) {
    return 0.5f * x * (1.0f + erff(x * 0.70710678118654752f));
}

// ---------------- fp32 -> bf16 weight cast, 8 elems/thread --------------------------
__global__ __launch_bounds__(256) void cast_f32_bf16(const float* __restrict__ src,
                                                     __bf16* __restrict__ dst, int n) {
    int i = (blockIdx.x * 256 + threadIdx.x) * 8;
    if (i >= n) return;
    floatx4 a = *(const floatx4*)(src + i);
    floatx4 b = *(const floatx4*)(src + i + 4);
    bf16x8 o;
    for (int j = 0; j < 4; ++j) { o[j] = (__bf16)a[j]; o[4 + j] = (__bf16)b[j]; }
    *(bf16x8*)(dst + i) = o;
}

// ---------------- LayerNorm: one wave per row of 1024; fp32 in, bf16 out ------------
__global__ __launch_bounds__(64) void ln_kernel(const float* __restrict__ x,
                                                const float* __restrict__ g,
                                                const float* __restrict__ b,
                                                __bf16* __restrict__ out) {
    int row = blockIdx.x, lane = threadIdx.x, base = lane * 16;
    const float* xr = x + (size_t)row * D_MODEL + base;
    float v[16];
    for (int j = 0; j < 4; ++j) {
        floatx4 a = *(const floatx4*)(xr + 4 * j);
        for (int i = 0; i < 4; ++i) v[4 * j + i] = a[i];
    }
    float s = 0.f, sq = 0.f;
    for (int i = 0; i < 16; ++i) { s += v[i]; sq += v[i] * v[i]; }
    for (int o = 1; o < 64; o <<= 1) { s += __shfl_xor(s, o); sq += __shfl_xor(sq, o); }
    float mu = s * (1.0f / D_MODEL);
    float var = sq * (1.0f / D_MODEL) - mu * mu;
    float rstd = rsqrtf(fmaxf(var, 0.f) + 1e-5f);

    const floatx4* gp = (const floatx4*)(g + base);
    const floatx4* bp = (const floatx4*)(b + base);
    bf16x8 o0, o1;
    for (int j = 0; j < 2; ++j) {
        floatx4 gv0 = gp[2 * j], gv1 = gp[2 * j + 1];
        floatx4 bv0 = bp[2 * j], bv1 = bp[2 * j + 1];
        for (int i = 0; i < 4; ++i) {
            float r0 = (v[8 * j + i] - mu) * rstd * gv0[i] + bv0[i];
            float r1 = (v[8 * j + 4 + i] - mu) * rstd * gv1[i] + bv1[i];
            if (j == 0) { o0[i] = (__bf16)r0; o0[4 + i] = (__bf16)r1; }
            else        { o1[i] = (__bf16)r0; o1[4 + i] = (__bf16)r1; }
        }
    }
    bf16x8* op = (bf16x8*)(out + (size_t)row * D_MODEL + base);
    op[0] = o0; op[1] = o1;
}

// ---------------- GEMM: C = A@W^T + bias (+gelu) (+res), 2-phase prefetch -----------
// A, W bf16 K-contiguous. 128x128 tile, BK=32, 4 waves, global_load_lds width=16.
// Double-buffered LDS, stage(k+1) issued right after the barrier so its latency
// hides under the K-step's ds_read+MFMA; ONE barrier per K-step (T3-minimum).
// KSPLIT>1: blockIdx.z takes a K-slice, raw fp32 partial -> out (z=0) / part1 (z=1);
// bias/res/gelu applied by reduce_k2 afterwards.
template <typename OutT, bool GELU, bool TRIBIAS, int KSPLIT>
__global__ __launch_bounds__(256) void gemm_bt(const __bf16* __restrict__ A,
                                               const __bf16* __restrict__ W,
                                               const float* __restrict__ bias0,
                                               const float* __restrict__ bias1,
                                               const float* __restrict__ bias2,
                                               const float* __restrict__ res,
                                               OutT* out, float* part1,
                                               int M, int N, int K) {
    __shared__ __bf16 As[2][128][32];
    __shared__ __bf16 Ws[2][128][32];

    int m0 = blockIdx.y * 128, n0 = blockIdx.x * 128;
    int t = threadIdx.x;
    int lane = t & 63, wave = t >> 6;
    int wm = (wave >> 1) * 64, wn = (wave & 1) * 64;
    int fr = lane & 15, quad = lane >> 4;
    int srow = t >> 2, scol = (t & 3) * 8;

    int Ks = K / KSPLIT;
    int kbeg = (KSPLIT > 1) ? blockIdx.z * Ks : 0;

    floatx4 acc[4][4] = {};

    const __bf16* Ab = A + (size_t)(m0 + srow) * K + kbeg + scol;
    const __bf16* Wb = W + (size_t)(n0 + srow) * K + kbeg + scol;

    auto stage = [&](int buf, int k0) {
        __builtin_amdgcn_global_load_lds((gbl_void_t*)(Ab + k0),
                                         (lds_void_t*)&As[buf][wave * 16][0], 16, 0, 0);
        __builtin_amdgcn_global_load_lds((gbl_void_t*)(Ab + (size_t)64 * K + k0),
                                         (lds_void_t*)&As[buf][64 + wave * 16][0], 16, 0, 0);
        __builtin_amdgcn_global_load_lds((gbl_void_t*)(Wb + k0),
                                         (lds_void_t*)&Ws[buf][wave * 16][0], 16, 0, 0);
        __builtin_amdgcn_global_load_lds((gbl_void_t*)(Wb + (size_t)64 * K + k0),
                                         (lds_void_t*)&Ws[buf][64 + wave * 16][0], 16, 0, 0);
    };

    stage(0, 0);
    int nsteps = Ks / 32;
    for (int s = 0; s < nsteps; ++s) {
        int cur = s & 1;
        __syncthreads();   // buf[cur] staged (vmcnt drained) + prior reads done
        if (s + 1 < nsteps) stage(cur ^ 1, (s + 1) * 32);

        bf16x8 af[4], wf[4];
#pragma unroll
        for (int i = 0; i < 4; ++i) af[i] = *(const bf16x8*)&As[cur][wm + i * 16 + fr][quad * 8];
#pragma unroll
        for (int i = 0; i < 4; ++i) wf[i] = *(const bf16x8*)&Ws[cur][wn + i * 16 + fr][quad * 8];
#pragma unroll
        for (int mi = 0; mi < 4; ++mi)
#pragma unroll
            for (int ni = 0; ni < 4; ++ni)
                acc[mi][ni] = __builtin_amdgcn_mfma_f32_16x16x32_bf16(af[mi], wf[ni], acc[mi][ni], 0, 0, 0);
    }

    if (KSPLIT > 1) {
        float* pb = (blockIdx.z == 0) ? (float*)out : part1;
#pragma unroll
        for (int ni = 0; ni < 4; ++ni) {
            int col = n0 + wn + ni * 16 + fr;
#pragma unroll
            for (int mi = 0; mi < 4; ++mi)
#pragma unroll
                for (int r = 0; r < 4; ++r) {
                    int row = m0 + wm + mi * 16 + quad * 4 + r;
                    pb[(size_t)row * N + col] = acc[mi][ni][r];
                }
        }
    } else {
#pragma unroll
        for (int ni = 0; ni < 4; ++ni) {
            int col = n0 + wn + ni * 16 + fr;
            const float* bp = bias0;
            int bcol = col;
            if (TRIBIAS) { bp = col < 1024 ? bias0 : (col < 2048 ? bias1 : bias2); bcol = col & 1023; }
            float bv = bp[bcol];
#pragma unroll
            for (int mi = 0; mi < 4; ++mi) {
#pragma unroll
                for (int r = 0; r < 4; ++r) {
                    int row = m0 + wm + mi * 16 + quad * 4 + r;
                    float v = acc[mi][ni][r] + bv;
                    if (GELU) v = gelu_exact(v);
                    if (res) v += res[(size_t)row * N + col];
                    out[(size_t)row * N + col] = (OutT)v;
                }
            }
        }
    }
}

// ---------------- split-K reduce: out = p0 + p1 + res + bias (N=1024 pow2) ----------
__global__ __launch_bounds__(256) void reduce_k2(const float* __restrict__ p0,
                                                 const float* p1,
                                                 const float* __restrict__ res,
                                                 const float* __restrict__ bias,
                                                 float* out) {
    int i = (blockIdx.x * 256 + threadIdx.x) * 4;
    floatx4 a = *(const floatx4*)(p0 + i);
    floatx4 b = *(const floatx4*)(p1 + i);
    floatx4 r = *(const floatx4*)(res + i);
    floatx4 bv = *(const floatx4*)(bias + (i & 1023));
    floatx4 o;
#pragma unroll
    for (int j = 0; j < 4; ++j) o[j] = a[j] + b[j] + r[j] + bv[j];
    *(floatx4*)(out + i) = o;
}

// ---------------- V transpose: qkv v-part [b][s][2048+h*64+d] -> vt[b][h][d][s] -----
__global__ __launch_bounds__(256) void transpose_v(const __bf16* __restrict__ qkv,
                                                   __bf16* __restrict__ vt) {
    __shared__ __bf16 tile[64][72];
    int b = blockIdx.z, h = blockIdx.y, s0 = blockIdx.x * 64;
    int t = threadIdx.x;
    int dl = (t & 7) * 8, sl = t >> 3;
    for (int p = 0; p < 2; ++p) {
        int s = sl + p * 32;
        bf16x8 val = *(const bf16x8*)(qkv + (size_t)(b * SEQ + s0 + s) * QKVS + 2048 + h * DK + dl);
        *(bf16x8*)&tile[s][dl] = val;
    }
    __syncthreads();
    int sl2 = (t & 7) * 8, d = t >> 3;
    for (int p = 0; p < 2; ++p) {
        int dd = d + p * 32;
        bf16x8 val;
        for (int j = 0; j < 8; ++j) val[j] = tile[sl2 + j][dd];
        *(bf16x8*)(vt + ((size_t)(b * NH + h) * DK + dd) * SEQ + s0 + sl2) = val;
    }
}

// ---------------- Flash attention, fragment-ordered LDS K/V -------------------------
// 1 wave = 16 q-rows, 128-key tiles staged once per block via global_load_lds,
// prefetched one tile ahead. LDS layout is FRAGMENT-ORDERED: 16 blocks of 1024B per
// K/V tile, each block = one MFMA fragment set, read at base + lane*16 (the ideal
// conflict-free pattern, immediate-offset addressing, no swizzle math). Staging
// exploits global_load_lds's per-lane SOURCE: the global address for staging-lane l
// is exactly what reading-lane l consumes:
//   K block (f,half): lane l <- K[key=f*16+(l&15)][d=(l>>4)*8+half*32 ..+8)
//   V block (c,ti):   lane l <- Vt[d=ti*16+(l&15)][key=c*32+(l>>4)*8 ..+8)
// Softmax in exp2 domain (m tracked in s*scale*log2e units): 1 fma + 1 v_exp per
// score (was mul+sub+mul+exp), tree-shaped max/sum reductions.
__global__ __launch_bounds__(256, 2) void attn_kernel(const __bf16* __restrict__ qkv,
                                                      const __bf16* __restrict__ vt,
                                                      __bf16* __restrict__ ctx) {
    __shared__ __bf16 Klds[8192];        // 16 blocks x 1024B, block (f,half)=f*2+half
    __shared__ __bf16 Vlds[8192];        // 16 blocks x 1024B, block (c,ti)=c*4+ti
    __shared__ __bf16 Plds[4][16][136];  // [wave][query][128 keys + 8 pad]
    int b = blockIdx.z, h = blockIdx.y;
    int wave = threadIdx.x >> 6, lane = threadIdx.x & 63;
    int q0 = blockIdx.x * 64 + wave * 16;
    int fr = lane & 15, quad = lane >> 4;
    const float sc2 = 0.18033688011112042f;   // (1/sqrt(64)) * log2(e)

    const __bf16* qp = qkv + (size_t)(b * SEQ + q0 + fr) * QKVS + h * DK + quad * 8;
    bf16x8 qf0 = *(const bf16x8*)qp;
    bf16x8 qf1 = *(const bf16x8*)(qp + 32);

    const __bf16* kg = qkv + (size_t)b * SEQ * QKVS + 1024 + h * DK;  // + key*QKVS + d
    const __bf16* vg = vt + (size_t)(b * NH + h) * DK * SEQ;          // + d*SEQ + key

    floatx4 o[4] = {};
    float m_i = -1e30f, l_i = 0.f;

    // stage one 128-key tile: each wave stages 4 K-blocks + 4 V-blocks (8 instrs)
    auto stage_tile = [&](int k0) {
#pragma unroll
        for (int p = 0; p < 4; ++p) {
            int bid = wave * 4 + p;
            int f = bid >> 1, half = bid & 1;
            __builtin_amdgcn_global_load_lds(
                (gbl_void_t*)(kg + (size_t)(k0 + f * 16 + fr) * QKVS + quad * 8 + half * 32),
                (lds_void_t*)&Klds[bid * 512], 16, 0, 0);
            int c = bid >> 2, ti = bid & 3;
            __builtin_amdgcn_global_load_lds(
                (gbl_void_t*)(vg + (size_t)(ti * 16 + fr) * SEQ + k0 + c * 32 + quad * 8),
                (lds_void_t*)&Vlds[bid * 512], 16, 0, 0);
        }
    };

    stage_tile(0);
    __syncthreads();   // drains vmcnt -> tile 0 in LDS

    for (int k0 = 0; k0 < SEQ; k0 += 128) {
        // ---- fragment reads: base + lane*16, conflict-free, imm offsets ----
        const __bf16* Kb = Klds + lane * 8;
        const __bf16* Vb = Vlds + lane * 8;
        bf16x8 kA[8], kB[8];
#pragma unroll
        for (int f = 0; f < 8; ++f) {
            kA[f] = *(const bf16x8*)(Kb + (f * 2 + 0) * 512);
            kB[f] = *(const bf16x8*)(Kb + (f * 2 + 1) * 512);
        }
        bf16x8 vf[4][4];
#pragma unroll
        for (int c = 0; c < 4; ++c)
#pragma unroll
            for (int ti = 0; ti < 4; ++ti)
                vf[c][ti] = *(const bf16x8*)(Vb + (c * 4 + ti) * 512);
        __syncthreads();   // all waves done reading K/V LDS

        // ---- issue next tile's stage; latency hides under compute below ----
        if (k0 + 128 < SEQ) stage_tile(k0 + 128);

        // ---- QK^T MFMA cluster: s[f] = scores keys f*16+quad*4+r, query fr ----
        floatx4 s[8];
#pragma unroll
        for (int f = 0; f < 8; ++f) {
            floatx4 z = {0.f, 0.f, 0.f, 0.f};
            z = __builtin_amdgcn_mfma_f32_16x16x32_bf16(kA[f], qf0, z, 0, 0, 0);
            s[f] = __builtin_amdgcn_mfma_f32_16x16x32_bf16(kB[f], qf1, z, 0, 0, 0);
        }

        // ---- online softmax (exp2 domain), tree reductions ----
        float fm[8];
#pragma unroll
        for (int f = 0; f < 8; ++f)
            fm[f] = fmaxf(fmaxf(s[f][0], s[f][1]), fmaxf(s[f][2], s[f][3]));
        float mx = fmaxf(fmaxf(fmaxf(fm[0], fm[1]), fmaxf(fm[2], fm[3])),
                         fmaxf(fmaxf(fm[4], fm[5]), fmaxf(fm[6], fm[7])));
        float mx2 = mx * sc2;
        mx2 = fmaxf(mx2, __shfl_xor(mx2, 16));
        mx2 = fmaxf(mx2, __shfl_xor(mx2, 32));
        float mn = fmaxf(m_i, mx2);
        float alpha = EXP2(m_i - mn);
        m_i = mn;
        float r0 = 0.f, r1 = 0.f, r2 = 0.f, r3 = 0.f;
#pragma unroll
        for (int f = 0; f < 8; ++f) {
            bf16x4 pk;
            float p0 = EXP2(fmaf(s[f][0], sc2, -mn));
            float p1 = EXP2(fmaf(s[f][1], sc2, -mn));
            float p2 = EXP2(fmaf(s[f][2], sc2, -mn));
            float p3 = EXP2(fmaf(s[f][3], sc2, -mn));
            r0 += p0; r1 += p1; r2 += p2; r3 += p3;
            pk[0] = (__bf16)p0; pk[1] = (__bf16)p1; pk[2] = (__bf16)p2; pk[3] = (__bf16)p3;
            *(bf16x4*)&Plds[wave][fr][f * 16 + quad * 4] = pk;   // ds_write_b64
        }
        float rs = (r0 + r1) + (r2 + r3);
        rs += __shfl_xor(rs, 16);
        rs += __shfl_xor(rs, 32);
        l_i = l_i * alpha + rs;
        // broadcast alpha to o-layout lanes (query quad*4+r held by lane quad*4+r)
        float aB[4];
#pragma unroll
        for (int r = 0; r < 4; ++r) aB[r] = __shfl(alpha, quad * 4 + r);
#pragma unroll
        for (int ti = 0; ti < 4; ++ti)
#pragma unroll
            for (int r = 0; r < 4; ++r) o[ti][r] *= aB[r];
        __threadfence_block();   // order wave-private LDS writes -> cross-lane reads

        // ---- PV: batch the 4 P ds_read_b128, then pure MFMA cluster ----
        bf16x8 pa[4];
#pragma unroll
        for (int c = 0; c < 4; ++c)
            pa[c] = *(const bf16x8*)&Plds[wave][fr][c * 32 + quad * 8];
#pragma unroll
        for (int c = 0; c < 4; ++c)
#pragma unroll
            for (int ti = 0; ti < 4; ++ti)
                o[ti] = __builtin_amdgcn_mfma_f32_16x16x32_bf16(pa[c], vf[c][ti], o[ti], 0, 0, 0);
        __threadfence_block();   // P reads done before next iteration's writes

        __syncthreads();   // drains vmcnt -> staged tile t+1 ready in LDS
    }
    float lB[4];
#pragma unroll
    for (int r = 0; r < 4; ++r) lB[r] = __shfl(l_i, quad * 4 + r);
#pragma unroll
    for (int ti = 0; ti < 4; ++ti)
#pragma unroll
        for (int r = 0; r < 4; ++r)
            ctx[(size_t)(b * SEQ + q0 + quad * 4 + r) * D_MODEL + h * DK + ti * 16 + fr] =
                (__bf16)(o[ti][r] / lB[r]);
}

// -----------------------------------------------------------------------------------
// Workspace 72 MiB:
//   [0,6M):   wqkvB    [6,8M): woB    [8,16M): w1B    [16,24M): w2B
//   [24,40M): h1 -> x1 fp32 trunk
//   [40,64M): qkv      [64,72M): vt
//   AO split-K partials:  [40,56M) + [56,72M)  (qkv/vt dead after attn)
//   ffh = [40,72M) after AO reduce
//   FF2 split-K partials: [0,16M) (wqkvB/woB/w1B dead) + d_out (h2 dead)
//   d_out:    ctx -> h2 -> FF2 partial1 -> final out
extern "C" void kernel_launch(void* const* d_in, const int* in_sizes, int n_in,
                              void* d_out, int out_size, void* d_ws, size_t ws_size,
                              hipStream_t stream) {
    const float* x   = (const float*)d_in[0];
    const float* wq  = (const float*)d_in[1];
    const float* bq  = (const float*)d_in[2];
    const float* wk  = (const float*)d_in[3];
    const float* bk  = (const float*)d_in[4];
    const float* wv  = (const float*)d_in[5];
    const float* bv  = (const float*)d_in[6];
    const float* wo  = (const float*)d_in[7];
    const float* bo  = (const float*)d_in[8];
    const float* w1  = (const float*)d_in[9];
    const float* b1  = (const float*)d_in[10];
    const float* w2  = (const float*)d_in[11];
    const float* b2  = (const float*)d_in[12];
    const float* g1  = (const float*)d_in[13];
    const float* be1 = (const float*)d_in[14];
    const float* g2  = (const float*)d_in[15];
    const float* be2 = (const float*)d_in[16];
    float* out = (float*)d_out;

    char* ws = (char*)d_ws;
    const size_t MB = 1024 * 1024;
    __bf16* wqkvB = (__bf16*)(ws);                 // [0,6M)
    __bf16* woB   = (__bf16*)(ws + 6 * MB);
    __bf16* w1B   = (__bf16*)(ws + 8 * MB);
    __bf16* w2B   = (__bf16*)(ws + 16 * MB);
    __bf16* h1    = (__bf16*)(ws + 24 * MB);       // dead after qkv-gemm
    float*  x1    = (float*)(ws + 24 * MB);        // fp32 trunk [24,40M)
    __bf16* qkv   = (__bf16*)(ws + 40 * MB);       // [40,64M)
    __bf16* vt    = (__bf16*)(ws + 64 * MB);       // [64,72M)
    __bf16* ffh   = (__bf16*)(ws + 40 * MB);       // [40,72M) after qkv+vt die
    float*  pA0   = (float*)(ws + 40 * MB);        // AO partial z=0
    float*  pA1   = (float*)(ws + 56 * MB);        // AO partial z=1
    float*  pF0   = (float*)(ws);                  // FF2 partial z=0 [0,16M)
    __bf16* ctx   = (__bf16*)d_out;                // d_out scratch [0,8M)
    __bf16* h2    = (__bf16*)d_out;                // d_out scratch (after ctx dies)

    const int NDD = D_MODEL * D_MODEL;   // 1M
    const int NDF = D_MODEL * DFF;       // 4M
    cast_f32_bf16<<<NDD / 2048, 256, 0, stream>>>(wq, wqkvB, NDD);
    cast_f32_bf16<<<NDD / 2048, 256, 0, stream>>>(wk, wqkvB + NDD, NDD);
    cast_f32_bf16<<<NDD / 2048, 256, 0, stream>>>(wv, wqkvB + 2 * NDD, NDD);
    cast_f32_bf16<<<NDD / 2048, 256, 0, stream>>>(wo, woB, NDD);
    cast_f32_bf16<<<NDF / 2048, 256, 0, stream>>>(w1, w1B, NDF);
    cast_f32_bf16<<<NDF / 2048, 256, 0, stream>>>(w2, w2B, NDF);

    dim3 gQKV(QKVS / 128, NTOK / 128);       // (24, 32) = 768 blocks
    dim3 gDz(D_MODEL / 128, NTOK / 128, 2);  // (8, 32, 2) = 512 blocks, split-K=2
    dim3 gF(DFF / 128, NTOK / 128);          // (32, 32) = 1024 blocks
    dim3 gAttn(SEQ / 64, NH, BATCH);         // (32, 16, 2)
    int gRed = NTOK * D_MODEL / (256 * 4);   // 4096 blocks

    // 1. h1 = LN(x, g1, be1)
    ln_kernel<<<NTOK, 64, 0, stream>>>(x, g1, be1, h1);
    // 2. qkv = h1 @ [wq;wk;wv]^T + [bq;bk;bv]   (fused, N=3072)
    gemm_bt<__bf16, false, true, 1><<<gQKV, 256, 0, stream>>>(h1, wqkvB, bq, bk, bv, nullptr, qkv, nullptr, NTOK, QKVS, D_MODEL);
    // 3. vt = transpose(v) per head
    transpose_v<<<gAttn, 256, 0, stream>>>(qkv, vt);
    // 4. ctx = softmax(q k^T / sqrt(dk)) v   (writes d_out)
    attn_kernel<<<gAttn, 256, 0, stream>>>(qkv, vt, ctx);
    // 5. x1 = x + ctx @ wo^T + bo   (split-K=2: partials over dead qkv/vt, then reduce)
    gemm_bt<float, false, false, 2><<<gDz, 256, 0, stream>>>(ctx, woB, nullptr, nullptr, nullptr, nullptr, pA0, pA1, NTOK, D_MODEL, D_MODEL);
    reduce_k2<<<gRed, 256, 0, stream>>>(pA0, pA1, x, bo, x1);
    // 6. h2 = LN(x1, g2, be2)   (d_out scratch)
    ln_kernel<<<NTOK, 64, 0, stream>>>(x1, g2, be2, h2);
    // 7. ffh = gelu(h2 @ w1^T + b1)   (full 32 MiB over qkv+vt)
    gemm_bt<__bf16, true, false, 1><<<gF, 256, 0, stream>>>(h2, w1B, b1, b1, b1, nullptr, ffh, nullptr, NTOK, DFF, D_MODEL);
    // 8. out = x1 + ffh @ w2^T + b2   (split-K=2: p0=[0,16M), p1=d_out, reduce in place)
    gemm_bt<float, false, false, 2><<<gDz, 256, 0, stream>>>(ffh, w2B, nullptr, nullptr, nullptr, nullptr, pF0, (float*)d_out, NTOK, D_MODEL, DFF);
    reduce_k2<<<gRed, 256, 0, stream>>>(pF0, (float*)d_out, x1, b2, out);
}

// Round 5
// 417.701 us; speedup vs baseline: 1.6914x; 1.0350x over previous
//
#include <hip/hip_runtime.h>

typedef __attribute__((ext_vector_type(8))) __bf16 bf16x8;
typedef __attribute__((ext_vector_type(4))) __bf16 bf16x4;
typedef __attribute__((ext_vector_type(4))) float floatx4;
typedef void __attribute__((address_space(3))) lds_void_t;
typedef const void __attribute__((address_space(1))) gbl_void_t;

#define D_MODEL 1024
#define SEQ     2048
#define BATCH   2
#define NH      16
#define DK      64
#define DFF     4096
#define NTOK    (BATCH * SEQ)   // 4096
#define QKVS    3072            // fused qkv row stride

#if __has_builtin(__builtin_amdgcn_exp2f)
#define EXP2(x) __builtin_amdgcn_exp2f(x)
#else
#define EXP2(x) exp2f(x)
#endif

__device__ __forceinline__ float gelu_exact(float x) {
    return 0.5f * x * (1.0f + erff(x * 0.70710678118654752f));
}

// ---------------- fp32 -> bf16 weight cast, 8 elems/thread --------------------------
__global__ __launch_bounds__(256) void cast_f32_bf16(const float* __restrict__ src,
                                                     __bf16* __restrict__ dst, int n) {
    int i = (blockIdx.x * 256 + threadIdx.x) * 8;
    if (i >= n) return;
    floatx4 a = *(const floatx4*)(src + i);
    floatx4 b = *(const floatx4*)(src + i + 4);
    bf16x8 o;
    for (int j = 0; j < 4; ++j) { o[j] = (__bf16)a[j]; o[4 + j] = (__bf16)b[j]; }
    *(bf16x8*)(dst + i) = o;
}

// ---------------- LayerNorm: one wave per row of 1024; fp32 in, bf16 out ------------
__global__ __launch_bounds__(64) void ln_kernel(const float* __restrict__ x,
                                                const float* __restrict__ g,
                                                const float* __restrict__ b,
                                                __bf16* __restrict__ out) {
    int row = blockIdx.x, lane = threadIdx.x, base = lane * 16;
    const float* xr = x + (size_t)row * D_MODEL + base;
    float v[16];
    for (int j = 0; j < 4; ++j) {
        floatx4 a = *(const floatx4*)(xr + 4 * j);
        for (int i = 0; i < 4; ++i) v[4 * j + i] = a[i];
    }
    float s = 0.f, sq = 0.f;
    for (int i = 0; i < 16; ++i) { s += v[i]; sq += v[i] * v[i]; }
    for (int o = 1; o < 64; o <<= 1) { s += __shfl_xor(s, o); sq += __shfl_xor(sq, o); }
    float mu = s * (1.0f / D_MODEL);
    float var = sq * (1.0f / D_MODEL) - mu * mu;
    float rstd = rsqrtf(fmaxf(var, 0.f) + 1e-5f);

    const floatx4* gp = (const floatx4*)(g + base);
    const floatx4* bp = (const floatx4*)(b + base);
    bf16x8 o0, o1;
    for (int j = 0; j < 2; ++j) {
        floatx4 gv0 = gp[2 * j], gv1 = gp[2 * j + 1];
        floatx4 bv0 = bp[2 * j], bv1 = bp[2 * j + 1];
        for (int i = 0; i < 4; ++i) {
            float r0 = (v[8 * j + i] - mu) * rstd * gv0[i] + bv0[i];
            float r1 = (v[8 * j + 4 + i] - mu) * rstd * gv1[i] + bv1[i];
            if (j == 0) { o0[i] = (__bf16)r0; o0[4 + i] = (__bf16)r1; }
            else        { o1[i] = (__bf16)r0; o1[4 + i] = (__bf16)r1; }
        }
    }
    bf16x8* op = (bf16x8*)(out + (size_t)row * D_MODEL + base);
    op[0] = o0; op[1] = o1;
}

// ---------------- GEMM: C = A@W^T + bias (+gelu) (+res), 2-phase prefetch -----------
// A, W bf16 K-contiguous. 128x128 tile, BK=32, 4 waves, global_load_lds width=16.
// Double-buffered LDS, stage(k+1) issued right after the barrier; ONE barrier/K-step.
// KSPLIT>1: blockIdx.z takes a K-slice, raw fp32 partial; reduce_k2 finishes.
template <typename OutT, bool GELU, bool TRIBIAS, int KSPLIT>
__global__ __launch_bounds__(256) void gemm_bt(const __bf16* __restrict__ A,
                                               const __bf16* __restrict__ W,
                                               const float* __restrict__ bias0,
                                               const float* __restrict__ bias1,
                                               const float* __restrict__ bias2,
                                               const float* __restrict__ res,
                                               OutT* out, float* part1,
                                               int M, int N, int K) {
    __shared__ __bf16 As[2][128][32];
    __shared__ __bf16 Ws[2][128][32];

    int m0 = blockIdx.y * 128, n0 = blockIdx.x * 128;
    int t = threadIdx.x;
    int lane = t & 63, wave = t >> 6;
    int wm = (wave >> 1) * 64, wn = (wave & 1) * 64;
    int fr = lane & 15, quad = lane >> 4;
    int srow = t >> 2, scol = (t & 3) * 8;

    int Ks = K / KSPLIT;
    int kbeg = (KSPLIT > 1) ? blockIdx.z * Ks : 0;

    floatx4 acc[4][4] = {};

    const __bf16* Ab = A + (size_t)(m0 + srow) * K + kbeg + scol;
    const __bf16* Wb = W + (size_t)(n0 + srow) * K + kbeg + scol;

    auto stage = [&](int buf, int k0) {
        __builtin_amdgcn_global_load_lds((gbl_void_t*)(Ab + k0),
                                         (lds_void_t*)&As[buf][wave * 16][0], 16, 0, 0);
        __builtin_amdgcn_global_load_lds((gbl_void_t*)(Ab + (size_t)64 * K + k0),
                                         (lds_void_t*)&As[buf][64 + wave * 16][0], 16, 0, 0);
        __builtin_amdgcn_global_load_lds((gbl_void_t*)(Wb + k0),
                                         (lds_void_t*)&Ws[buf][wave * 16][0], 16, 0, 0);
        __builtin_amdgcn_global_load_lds((gbl_void_t*)(Wb + (size_t)64 * K + k0),
                                         (lds_void_t*)&Ws[buf][64 + wave * 16][0], 16, 0, 0);
    };

    stage(0, 0);
    int nsteps = Ks / 32;
    for (int s = 0; s < nsteps; ++s) {
        int cur = s & 1;
        __syncthreads();   // buf[cur] staged (vmcnt drained) + prior reads done
        if (s + 1 < nsteps) stage(cur ^ 1, (s + 1) * 32);

        bf16x8 af[4], wf[4];
#pragma unroll
        for (int i = 0; i < 4; ++i) af[i] = *(const bf16x8*)&As[cur][wm + i * 16 + fr][quad * 8];
#pragma unroll
        for (int i = 0; i < 4; ++i) wf[i] = *(const bf16x8*)&Ws[cur][wn + i * 16 + fr][quad * 8];
#pragma unroll
        for (int mi = 0; mi < 4; ++mi)
#pragma unroll
            for (int ni = 0; ni < 4; ++ni)
                acc[mi][ni] = __builtin_amdgcn_mfma_f32_16x16x32_bf16(af[mi], wf[ni], acc[mi][ni], 0, 0, 0);
    }

    if (KSPLIT > 1) {
        float* pb = (blockIdx.z == 0) ? (float*)out : part1;
#pragma unroll
        for (int ni = 0; ni < 4; ++ni) {
            int col = n0 + wn + ni * 16 + fr;
#pragma unroll
            for (int mi = 0; mi < 4; ++mi)
#pragma unroll
                for (int r = 0; r < 4; ++r) {
                    int row = m0 + wm + mi * 16 + quad * 4 + r;
                    pb[(size_t)row * N + col] = acc[mi][ni][r];
                }
        }
    } else {
#pragma unroll
        for (int ni = 0; ni < 4; ++ni) {
            int col = n0 + wn + ni * 16 + fr;
            const float* bp = bias0;
            int bcol = col;
            if (TRIBIAS) { bp = col < 1024 ? bias0 : (col < 2048 ? bias1 : bias2); bcol = col & 1023; }
            float bv = bp[bcol];
#pragma unroll
            for (int mi = 0; mi < 4; ++mi) {
#pragma unroll
                for (int r = 0; r < 4; ++r) {
                    int row = m0 + wm + mi * 16 + quad * 4 + r;
                    float v = acc[mi][ni][r] + bv;
                    if (GELU) v = gelu_exact(v);
                    if (res) v += res[(size_t)row * N + col];
                    out[(size_t)row * N + col] = (OutT)v;
                }
            }
        }
    }
}

// ---------------- split-K reduce: out = p0 + p1 + res + bias (N=1024 pow2) ----------
__global__ __launch_bounds__(256) void reduce_k2(const float* __restrict__ p0,
                                                 const float* p1,
                                                 const float* __restrict__ res,
                                                 const float* __restrict__ bias,
                                                 float* out) {
    int i = (blockIdx.x * 256 + threadIdx.x) * 4;
    floatx4 a = *(const floatx4*)(p0 + i);
    floatx4 b = *(const floatx4*)(p1 + i);
    floatx4 r = *(const floatx4*)(res + i);
    floatx4 bv = *(const floatx4*)(bias + (i & 1023));
    floatx4 o;
#pragma unroll
    for (int j = 0; j < 4; ++j) o[j] = a[j] + b[j] + r[j] + bv[j];
    *(floatx4*)(out + i) = o;
}

// ---------------- V transpose: qkv v-part [b][s][2048+h*64+d] -> vt[b][h][d][s] -----
__global__ __launch_bounds__(256) void transpose_v(const __bf16* __restrict__ qkv,
                                                   __bf16* __restrict__ vt) {
    __shared__ __bf16 tile[64][72];
    int b = blockIdx.z, h = blockIdx.y, s0 = blockIdx.x * 64;
    int t = threadIdx.x;
    int dl = (t & 7) * 8, sl = t >> 3;
    for (int p = 0; p < 2; ++p) {
        int s = sl + p * 32;
        bf16x8 val = *(const bf16x8*)(qkv + (size_t)(b * SEQ + s0 + s) * QKVS + 2048 + h * DK + dl);
        *(bf16x8*)&tile[s][dl] = val;
    }
    __syncthreads();
    int sl2 = (t & 7) * 8, d = t >> 3;
    for (int p = 0; p < 2; ++p) {
        int dd = d + p * 32;
        bf16x8 val;
        for (int j = 0; j < 8; ++j) val[j] = tile[sl2 + j][dd];
        *(bf16x8*)(vt + ((size_t)(b * NH + h) * DK + dd) * SEQ + s0 + sl2) = val;
    }
}

// ---------------- Flash attention, 32 queries/wave, fragment-ordered LDS K/V --------
// 1 wave = 32 q-rows (two 16-row halves sharing one K/V tile read): the per-iteration
// fixed tax (2 barriers, vmcnt drain, shfl chains, Plds roundtrip, LDS first-use
// latency) is amortized over 2x the MFMA+softmax work. 512 blocks = 2/CU, all
// resident (LDS 66KB). Register choreography keeps peak ~<200 VGPR:
//   read K frags -> QK h0 -> softmax h0 (s dies) -> QK h1 -> read V frags (K dies)
//   -> barrier -> stage(t+1) -> softmax h1 -> fence -> PV h0+h1 -> fence -> barrier
// so the staged loads fly under softmax h1 + PV (~650 cyc).
// LDS fragment-ordered blocks (1024B, read at base+lane*16, conflict-free):
//   K block (f,half): lane l <- K[key=f*16+(l&15)][d=(l>>4)*8+half*32 ..+8)
//   V block (c,ti):   lane l <- Vt[d=ti*16+(l&15)][key=c*32+(l>>4)*8 ..+8)
// Softmax in exp2 domain: 1 fma + 1 v_exp per score, tree reductions.
__global__ __launch_bounds__(256, 2) void attn_kernel(const __bf16* __restrict__ qkv,
                                                      const __bf16* __restrict__ vt,
                                                      __bf16* __restrict__ ctx) {
    __shared__ __bf16 Klds[8192];        // 16 blocks x 1024B, block (f,half)=f*2+half
    __shared__ __bf16 Vlds[8192];        // 16 blocks x 1024B, block (c,ti)=c*4+ti
    __shared__ __bf16 Plds[4][32][136];  // [wave][query 32][128 keys + 8 pad]
    int b = blockIdx.z, h = blockIdx.y;
    int wave = threadIdx.x >> 6, lane = threadIdx.x & 63;
    int q0 = blockIdx.x * 128 + wave * 32;
    int fr = lane & 15, quad = lane >> 4;
    const float sc2 = 0.18033688011112042f;   // (1/sqrt(64)) * log2(e)

    const __bf16* qp0 = qkv + (size_t)(b * SEQ + q0 + fr) * QKVS + h * DK + quad * 8;
    const __bf16* qp1 = qp0 + (size_t)16 * QKVS;
    bf16x8 qA0 = *(const bf16x8*)qp0, qB0 = *(const bf16x8*)(qp0 + 32);
    bf16x8 qA1 = *(const bf16x8*)qp1, qB1 = *(const bf16x8*)(qp1 + 32);

    const __bf16* kg = qkv + (size_t)b * SEQ * QKVS + 1024 + h * DK;  // + key*QKVS + d
    const __bf16* vg = vt + (size_t)(b * NH + h) * DK * SEQ;          // + d*SEQ + key

    floatx4 o[8] = {};   // [hh*4+ti]: row=query hh*16+quad*4+r, col=d ti*16+fr
    float m0q = -1e30f, l0q = 0.f, m1q = -1e30f, l1q = 0.f;

    // stage one 128-key tile: each wave stages 4 K-blocks + 4 V-blocks (8 instrs)
    auto stage_tile = [&](int k0) {
#pragma unroll
        for (int p = 0; p < 4; ++p) {
            int bid = wave * 4 + p;
            int f = bid >> 1, half = bid & 1;
            __builtin_amdgcn_global_load_lds(
                (gbl_void_t*)(kg + (size_t)(k0 + f * 16 + fr) * QKVS + quad * 8 + half * 32),
                (lds_void_t*)&Klds[bid * 512], 16, 0, 0);
            int c = bid >> 2, ti = bid & 3;
            __builtin_amdgcn_global_load_lds(
                (gbl_void_t*)(vg + (size_t)(ti * 16 + fr) * SEQ + k0 + c * 32 + quad * 8),
                (lds_void_t*)&Vlds[bid * 512], 16, 0, 0);
        }
    };

    stage_tile(0);
    __syncthreads();   // drains vmcnt -> tile 0 in LDS

    for (int k0 = 0; k0 < SEQ; k0 += 128) {
        const __bf16* Kb = Klds + lane * 8;
        const __bf16* Vb = Vlds + lane * 8;
        // ---- K fragment reads: base + lane*16, conflict-free ----
        bf16x8 kA[8], kB[8];
#pragma unroll
        for (int f = 0; f < 8; ++f) {
            kA[f] = *(const bf16x8*)(Kb + (f * 2 + 0) * 512);
            kB[f] = *(const bf16x8*)(Kb + (f * 2 + 1) * 512);
        }

        // ---- QK^T half 0 ----
        floatx4 s[8];
#pragma unroll
        for (int f = 0; f < 8; ++f) {
            floatx4 z = {0.f, 0.f, 0.f, 0.f};
            z = __builtin_amdgcn_mfma_f32_16x16x32_bf16(kA[f], qA0, z, 0, 0, 0);
            s[f] = __builtin_amdgcn_mfma_f32_16x16x32_bf16(kB[f], qB0, z, 0, 0, 0);
        }
        // ---- softmax half 0 (exp2 domain, tree reductions); s dies here ----
        {
            float fm[8];
#pragma unroll
            for (int f = 0; f < 8; ++f)
                fm[f] = fmaxf(fmaxf(s[f][0], s[f][1]), fmaxf(s[f][2], s[f][3]));
            float mx = fmaxf(fmaxf(fmaxf(fm[0], fm[1]), fmaxf(fm[2], fm[3])),
                             fmaxf(fmaxf(fm[4], fm[5]), fmaxf(fm[6], fm[7])));
            float mx2 = mx * sc2;
            mx2 = fmaxf(mx2, __shfl_xor(mx2, 16));
            mx2 = fmaxf(mx2, __shfl_xor(mx2, 32));
            float mn = fmaxf(m0q, mx2);
            float alpha = EXP2(m0q - mn);
            m0q = mn;
            float r0 = 0.f, r1 = 0.f, r2 = 0.f, r3 = 0.f;
#pragma unroll
            for (int f = 0; f < 8; ++f) {
                bf16x4 pk;
                float p0 = EXP2(fmaf(s[f][0], sc2, -mn));
                float p1 = EXP2(fmaf(s[f][1], sc2, -mn));
                float p2 = EXP2(fmaf(s[f][2], sc2, -mn));
                float p3 = EXP2(fmaf(s[f][3], sc2, -mn));
                r0 += p0; r1 += p1; r2 += p2; r3 += p3;
                pk[0] = (__bf16)p0; pk[1] = (__bf16)p1; pk[2] = (__bf16)p2; pk[3] = (__bf16)p3;
                *(bf16x4*)&Plds[wave][fr][f * 16 + quad * 4] = pk;
            }
            float rs = (r0 + r1) + (r2 + r3);
            rs += __shfl_xor(rs, 16);
            rs += __shfl_xor(rs, 32);
            l0q = l0q * alpha + rs;
            float aB[4];
#pragma unroll
            for (int r = 0; r < 4; ++r) aB[r] = __shfl(alpha, quad * 4 + r);
#pragma unroll
            for (int ti = 0; ti < 4; ++ti)
#pragma unroll
                for (int r = 0; r < 4; ++r) o[ti][r] *= aB[r];
        }

        // ---- QK^T half 1 (reuses s; kA/kB die after this) ----
        floatx4 s1[8];
#pragma unroll
        for (int f = 0; f < 8; ++f) {
            floatx4 z = {0.f, 0.f, 0.f, 0.f};
            z = __builtin_amdgcn_mfma_f32_16x16x32_bf16(kA[f], qA1, z, 0, 0, 0);
            s1[f] = __builtin_amdgcn_mfma_f32_16x16x32_bf16(kB[f], qB1, z, 0, 0, 0);
        }

        // ---- V fragment reads (K regs free) ----
        bf16x8 vf[4][4];
#pragma unroll
        for (int c = 0; c < 4; ++c)
#pragma unroll
            for (int ti = 0; ti < 4; ++ti)
                vf[c][ti] = *(const bf16x8*)(Vb + (c * 4 + ti) * 512);

        __syncthreads();   // all waves done reading K/V LDS
        if (k0 + 128 < SEQ) stage_tile(k0 + 128);   // loads fly under softmax h1 + PV

        // ---- softmax half 1 ----
        {
            float fm[8];
#pragma unroll
            for (int f = 0; f < 8; ++f)
                fm[f] = fmaxf(fmaxf(s1[f][0], s1[f][1]), fmaxf(s1[f][2], s1[f][3]));
            float mx = fmaxf(fmaxf(fmaxf(fm[0], fm[1]), fmaxf(fm[2], fm[3])),
                             fmaxf(fmaxf(fm[4], fm[5]), fmaxf(fm[6], fm[7])));
            float mx2 = mx * sc2;
            mx2 = fmaxf(mx2, __shfl_xor(mx2, 16));
            mx2 = fmaxf(mx2, __shfl_xor(mx2, 32));
            float mn = fmaxf(m1q, mx2);
            float alpha = EXP2(m1q - mn);
            m1q = mn;
            float r0 = 0.f, r1 = 0.f, r2 = 0.f, r3 = 0.f;
#pragma unroll
            for (int f = 0; f < 8; ++f) {
                bf16x4 pk;
                float p0 = EXP2(fmaf(s1[f][0], sc2, -mn));
                float p1 = EXP2(fmaf(s1[f][1], sc2, -mn));
                float p2 = EXP2(fmaf(s1[f][2], sc2, -mn));
                float p3 = EXP2(fmaf(s1[f][3], sc2, -mn));
                r0 += p0; r1 += p1; r2 += p2; r3 += p3;
                pk[0] = (__bf16)p0; pk[1] = (__bf16)p1; pk[2] = (__bf16)p2; pk[3] = (__bf16)p3;
                *(bf16x4*)&Plds[wave][16 + fr][f * 16 + quad * 4] = pk;
            }
            float rs = (r0 + r1) + (r2 + r3);
            rs += __shfl_xor(rs, 16);
            rs += __shfl_xor(rs, 32);
            l1q = l1q * alpha + rs;
            float aB[4];
#pragma unroll
            for (int r = 0; r < 4; ++r) aB[r] = __shfl(alpha, quad * 4 + r);
#pragma unroll
            for (int ti = 0; ti < 4; ++ti)
#pragma unroll
                for (int r = 0; r < 4; ++r) o[4 + ti][r] *= aB[r];
        }
        __threadfence_block();   // order wave-private Plds writes -> cross-lane reads

        // ---- PV both halves: batched pa reads, then pure MFMA clusters ----
        bf16x8 pa0[4], pa1[4];
#pragma unroll
        for (int c = 0; c < 4; ++c) {
            pa0[c] = *(const bf16x8*)&Plds[wave][fr][c * 32 + quad * 8];
            pa1[c] = *(const bf16x8*)&Plds[wave][16 + fr][c * 32 + quad * 8];
        }
#pragma unroll
        for (int c = 0; c < 4; ++c)
#pragma unroll
            for (int ti = 0; ti < 4; ++ti) {
                o[ti]     = __builtin_amdgcn_mfma_f32_16x16x32_bf16(pa0[c], vf[c][ti], o[ti], 0, 0, 0);
                o[4 + ti] = __builtin_amdgcn_mfma_f32_16x16x32_bf16(pa1[c], vf[c][ti], o[4 + ti], 0, 0, 0);
            }
        __threadfence_block();   // P reads done before next iteration's writes

        __syncthreads();   // drains vmcnt -> staged tile t+1 ready in LDS
    }
    float lB0[4], lB1[4];
#pragma unroll
    for (int r = 0; r < 4; ++r) {
        lB0[r] = __shfl(l0q, quad * 4 + r);
        lB1[r] = __shfl(l1q, quad * 4 + r);
    }
#pragma unroll
    for (int ti = 0; ti < 4; ++ti)
#pragma unroll
        for (int r = 0; r < 4; ++r) {
            ctx[(size_t)(b * SEQ + q0 + quad * 4 + r) * D_MODEL + h * DK + ti * 16 + fr] =
                (__bf16)(o[ti][r] / lB0[r]);
            ctx[(size_t)(b * SEQ + q0 + 16 + quad * 4 + r) * D_MODEL + h * DK + ti * 16 + fr] =
                (__bf16)(o[4 + ti][r] / lB1[r]);
        }
}

// -----------------------------------------------------------------------------------
// Workspace 72 MiB:
//   [0,6M):   wqkvB    [6,8M): woB    [8,16M): w1B    [16,24M): w2B
//   [24,40M): h1 -> x1 fp32 trunk
//   [40,64M): qkv      [64,72M): vt
//   AO split-K partials:  [40,56M) + [56,72M)  (qkv/vt dead after attn)
//   ffh = [40,72M) after AO reduce
//   FF2 split-K partials: [0,16M) (wqkvB/woB/w1B dead) + d_out (h2 dead)
//   d_out:    ctx -> h2 -> FF2 partial1 -> final out
extern "C" void kernel_launch(void* const* d_in, const int* in_sizes, int n_in,
                              void* d_out, int out_size, void* d_ws, size_t ws_size,
                              hipStream_t stream) {
    const float* x   = (const float*)d_in[0];
    const float* wq  = (const float*)d_in[1];
    const float* bq  = (const float*)d_in[2];
    const float* wk  = (const float*)d_in[3];
    const float* bk  = (const float*)d_in[4];
    const float* wv  = (const float*)d_in[5];
    const float* bv  = (const float*)d_in[6];
    const float* wo  = (const float*)d_in[7];
    const float* bo  = (const float*)d_in[8];
    const float* w1  = (const float*)d_in[9];
    const float* b1  = (const float*)d_in[10];
    const float* w2  = (const float*)d_in[11];
    const float* b2  = (const float*)d_in[12];
    const float* g1  = (const float*)d_in[13];
    const float* be1 = (const float*)d_in[14];
    const float* g2  = (const float*)d_in[15];
    const float* be2 = (const float*)d_in[16];
    float* out = (float*)d_out;

    char* ws = (char*)d_ws;
    const size_t MB = 1024 * 1024;
    __bf16* wqkvB = (__bf16*)(ws);                 // [0,6M)
    __bf16* woB   = (__bf16*)(ws + 6 * MB);
    __bf16* w1B   = (__bf16*)(ws + 8 * MB);
    __bf16* w2B   = (__bf16*)(ws + 16 * MB);
    __bf16* h1    = (__bf16*)(ws + 24 * MB);       // dead after qkv-gemm
    float*  x1    = (float*)(ws + 24 * MB);        // fp32 trunk [24,40M)
    __bf16* qkv   = (__bf16*)(ws + 40 * MB);       // [40,64M)
    __bf16* vt    = (__bf16*)(ws + 64 * MB);       // [64,72M)
    __bf16* ffh   = (__bf16*)(ws + 40 * MB);       // [40,72M) after qkv+vt die
    float*  pA0   = (float*)(ws + 40 * MB);        // AO partial z=0
    float*  pA1   = (float*)(ws + 56 * MB);        // AO partial z=1
    float*  pF0   = (float*)(ws);                  // FF2 partial z=0 [0,16M)
    __bf16* ctx   = (__bf16*)d_out;                // d_out scratch [0,8M)
    __bf16* h2    = (__bf16*)d_out;                // d_out scratch (after ctx dies)

    const int NDD = D_MODEL * D_MODEL;   // 1M
    const int NDF = D_MODEL * DFF;       // 4M
    cast_f32_bf16<<<NDD / 2048, 256, 0, stream>>>(wq, wqkvB, NDD);
    cast_f32_bf16<<<NDD / 2048, 256, 0, stream>>>(wk, wqkvB + NDD, NDD);
    cast_f32_bf16<<<NDD / 2048, 256, 0, stream>>>(wv, wqkvB + 2 * NDD, NDD);
    cast_f32_bf16<<<NDD / 2048, 256, 0, stream>>>(wo, woB, NDD);
    cast_f32_bf16<<<NDF / 2048, 256, 0, stream>>>(w1, w1B, NDF);
    cast_f32_bf16<<<NDF / 2048, 256, 0, stream>>>(w2, w2B, NDF);

    dim3 gQKV(QKVS / 128, NTOK / 128);       // (24, 32) = 768 blocks
    dim3 gDz(D_MODEL / 128, NTOK / 128, 2);  // (8, 32, 2) = 512 blocks, split-K=2
    dim3 gF(DFF / 128, NTOK / 128);          // (32, 32) = 1024 blocks
    dim3 gTr(SEQ / 64, NH, BATCH);           // (32, 16, 2) transpose_v
    dim3 gAttn(SEQ / 128, NH, BATCH);        // (16, 16, 2) = 512 blocks, 2/CU
    int gRed = NTOK * D_MODEL / (256 * 4);   // 4096 blocks

    // 1. h1 = LN(x, g1, be1)
    ln_kernel<<<NTOK, 64, 0, stream>>>(x, g1, be1, h1);
    // 2. qkv = h1 @ [wq;wk;wv]^T + [bq;bk;bv]   (fused, N=3072)
    gemm_bt<__bf16, false, true, 1><<<gQKV, 256, 0, stream>>>(h1, wqkvB, bq, bk, bv, nullptr, qkv, nullptr, NTOK, QKVS, D_MODEL);
    // 3. vt = transpose(v) per head
    transpose_v<<<gTr, 256, 0, stream>>>(qkv, vt);
    // 4. ctx = softmax(q k^T / sqrt(dk)) v   (writes d_out)
    attn_kernel<<<gAttn, 256, 0, stream>>>(qkv, vt, ctx);
    // 5. x1 = x + ctx @ wo^T + bo   (split-K=2: partials over dead qkv/vt, then reduce)
    gemm_bt<float, false, false, 2><<<gDz, 256, 0, stream>>>(ctx, woB, nullptr, nullptr, nullptr, nullptr, pA0, pA1, NTOK, D_MODEL, D_MODEL);
    reduce_k2<<<gRed, 256, 0, stream>>>(pA0, pA1, x, bo, x1);
    // 6. h2 = LN(x1, g2, be2)   (d_out scratch)
    ln_kernel<<<NTOK, 64, 0, stream>>>(x1, g2, be2, h2);
    // 7. ffh = gelu(h2 @ w1^T + b1)   (full 32 MiB over qkv+vt)
    gemm_bt<__bf16, true, false, 1><<<gF, 256, 0, stream>>>(h2, w1B, b1, b1, b1, nullptr, ffh, nullptr, NTOK, DFF, D_MODEL);
    // 8. out = x1 + ffh @ w2^T + b2   (split-K=2: p0=[0,16M), p1=d_out, reduce in place)
    gemm_bt<float, false, false, 2><<<gDz, 256, 0, stream>>>(ffh, w2B, nullptr, nullptr, nullptr, nullptr, pF0, (float*)d_out, NTOK, D_MODEL, DFF);
    reduce_k2<<<gRed, 256, 0, stream>>>(pF0, (float*)d_out, x1, b2, out);
}